// Round 14
// baseline (246.497 us; speedup 1.0000x reference)
//
#include <hip/hip_runtime.h>
#include <hip/hip_bf16.h>

typedef unsigned int u32;
typedef unsigned short u16;
typedef __bf16 bf16x8 __attribute__((ext_vector_type(8)));
typedef float f32x4 __attribute__((ext_vector_type(4)));
typedef float f32x16 __attribute__((ext_vector_type(16)));

typedef const __attribute__((address_space(1))) u32 gas_u32;
typedef __attribute__((address_space(3))) u32 las_u32;

#define ST 4096   // total KV length

__device__ __forceinline__ u16 f2bf(float f) {
    u32 u = __builtin_bit_cast(u32, f);
    u32 r = (u + 0x7FFFu + ((u >> 16) & 1u)) >> 16;
    return (u16)r;
}

__device__ __forceinline__ u32 cvtpk(float lo, float hi) {
    u32 r;
    asm("v_cvt_pk_bf16_f32 %0, %1, %2" : "=v"(r) : "v"(lo), "v"(hi));
    return r;
}

__device__ __forceinline__ uint4 pack8(float4 a, float4 b) {
    uint4 o;
    u16* e = (u16*)&o;
    e[0] = f2bf(a.x); e[1] = f2bf(a.y); e[2] = f2bf(a.z); e[3] = f2bf(a.w);
    e[4] = f2bf(b.x); e[5] = f2bf(b.y); e[6] = f2bf(b.z); e[7] = f2bf(b.w);
    return o;
}

__device__ __forceinline__ void gload_lds16(const u16* g, u16* l) {
    __builtin_amdgcn_global_load_lds((gas_u32*)g, (las_u32*)l, 16, 0, 0);
}

// ============ x: f32 -> bf16, layout-preserving ============
__global__ __launch_bounds__(256) void k_cvt_x(const float* __restrict__ x, u16* __restrict__ xb) {
    int t = blockIdx.x * 256 + threadIdx.x;
    const float4* s = (const float4*)(x + t * 8);
    *(uint4*)(xb + t * 8) = pack8(s[0], s[1]);
}

// ============ weight transpose + convert: WT[e][d] = bf16(W[d][e]) ============
__global__ __launch_bounds__(256) void k_transpose(const float* w0, const float* w1,
                                                   const float* w2, const float* w3, u16* wt) {
    int z = blockIdx.z;
    const float* W = (z == 0) ? w0 : (z == 1) ? w1 : (z == 2) ? w2 : w3;
    u16* WT = wt + z * (1024 * 1024);
    __shared__ u16 tile[64 * 72];
    int t = threadIdx.x;
    int tr = blockIdx.y * 64, tc = blockIdx.x * 64;
#pragma unroll
    for (int p = 0; p < 2; ++p) {
        int r = (t >> 3) + p * 32, c8 = (t & 7) * 8;
        const float4* src = (const float4*)&W[(tr + r) * 1024 + tc + c8];
        *(uint4*)&tile[r * 72 + c8] = pack8(src[0], src[1]);
    }
    __syncthreads();
#pragma unroll
    for (int p = 0; p < 2; ++p) {
        int r = (t >> 3) + p * 32, c8 = (t & 7) * 8;
        uint4 vv;
        u16* e = (u16*)&vv;
#pragma unroll
        for (int j = 0; j < 8; ++j) e[j] = tile[(c8 + j) * 72 + r];
        *(uint4*)&WT[(tc + r) * 1024 + tr + c8] = vv;
    }
}

// ============ tiered cache copy: f32 caches + bf16 K + TRANSPOSED bf16 V^T ============
__global__ __launch_bounds__(256) void k_copy_cache_t(const float* __restrict__ k_in,
                                                      const float* __restrict__ v_in,
                                                      float* kc, float* vc,
                                                      u16* kb, u16* vbT) {
    __shared__ u16 tile[64 * 72];
    const int t = threadIdx.x;
    const int kt = blockIdx.x, bh = blockIdx.y;
    const int r = t >> 3, c8 = (t & 7) * 8;
#pragma unroll
    for (int p = 0; p < 2; ++p) {
        int rr = r + p * 32;
        int srow = (bh * 2048 + kt * 64 + rr) * 64 + c8;
        int drow = (bh * 4096 + kt * 64 + rr) * 64 + c8;
        const float4* ks = (const float4*)&k_in[srow];
        const float4* vs = (const float4*)&v_in[srow];
        float4 k0 = ks[0], k1 = ks[1], v0 = vs[0], v1 = vs[1];
        *(float4*)&kc[drow] = k0; *(float4*)&kc[drow + 4] = k1;
        *(float4*)&vc[drow] = v0; *(float4*)&vc[drow + 4] = v1;
        *(uint4*)&kb[drow] = pack8(k0, k1);
        *(uint4*)&tile[rr * 72 + c8] = pack8(v0, v1);
    }
    __syncthreads();
#pragma unroll
    for (int p = 0; p < 2; ++p) {
        int dd = r + p * 32;
        uint4 vv;
        u16* e = (u16*)&vv;
#pragma unroll
        for (int j = 0; j < 8; ++j) e[j] = tile[(c8 + j) * 72 + dd];
        *(uint4*)&vbT[(bh * 64 + dd) * 4096 + kt * 64 + c8] = vv;
    }
}

// ============ transpose new-half V rows: vbn [bh][2048][64] -> vbT cols 2048+ ============
__global__ __launch_bounds__(256) void k_vt(const u16* __restrict__ vbn, u16* __restrict__ vbT) {
    __shared__ u16 tile[64 * 72];
    const int t = threadIdx.x;
    const int kt = blockIdx.x, bh = blockIdx.y;
    const int r = t >> 3, c8 = (t & 7) * 8;
#pragma unroll
    for (int p = 0; p < 2; ++p) {
        int rr = r + p * 32;
        *(uint4*)&tile[rr * 72 + c8] =
            *(const uint4*)&vbn[(bh * 2048 + kt * 64 + rr) * 64 + c8];
    }
    __syncthreads();
#pragma unroll
    for (int p = 0; p < 2; ++p) {
        int dd = r + p * 32;
        uint4 vv;
        u16* e = (u16*)&vv;
#pragma unroll
        for (int j = 0; j < 8; ++j) e[j] = tile[(c8 + j) * 72 + dd];
        *(uint4*)&vbT[(bh * 64 + dd) * 4096 + 2048 + kt * 64 + c8] = vv;
    }
}

// ============ MFMA GEMM mainloop (m97-pattern): C(128x128) += A * BT^T ============
__device__ __forceinline__ void gemm_loop(const u16* A, const u16* BT, int mrow, int ncol,
                                          u16* lds_a, u16* lds_b, f32x4 (&acc)[4][4]) {
    const int t = threadIdx.x;
    const int lane = t & 63;
    const int w = t >> 6;
    const int wm = (w >> 1) * 64, wn = (w & 1) * 64;
    const int l15 = lane & 15, lg = lane >> 4;

    const u16* gA = A + (mrow + (t >> 2)) * 1024 + (t & 3) * 8;
    const u16* gB = BT + (ncol + (t >> 2)) * 1024 + (t & 3) * 8;
    u16* la = lds_a + t * 8;
    u16* lb = lds_b + t * 8;

    for (int k0 = 0; k0 < 1024; k0 += 32) {
        gload_lds16(gA + k0, la);
        gload_lds16(gA + k0 + 64 * 1024, la + 64 * 32);
        gload_lds16(gB + k0, lb);
        gload_lds16(gB + k0 + 64 * 1024, lb + 64 * 32);
        __syncthreads();
        bf16x8 af[4], bfr[4];
#pragma unroll
        for (int m = 0; m < 4; ++m)
            af[m] = *(const bf16x8*)&lds_a[(wm + m * 16 + l15) * 32 + lg * 8];
#pragma unroll
        for (int n = 0; n < 4; ++n)
            bfr[n] = *(const bf16x8*)&lds_b[(wn + n * 16 + l15) * 32 + lg * 8];
#pragma unroll
        for (int m = 0; m < 4; ++m)
#pragma unroll
            for (int n = 0; n < 4; ++n)
                acc[m][n] = __builtin_amdgcn_mfma_f32_16x16x32_bf16(af[m], bfr[n], acc[m][n], 0, 0, 0);
        __syncthreads();
    }
}

// ============ QKV projection with scatter ============
__global__ __launch_bounds__(256) void k_gemm_qkv(const u16* X, const u16* WT,
                                                  u16* qb, float* kc, float* vc,
                                                  u16* kb, u16* vbn) {
    __shared__ u16 lds_a[128 * 32];
    __shared__ u16 lds_b[128 * 32];
    const int z = blockIdx.z;
    const int mrow = blockIdx.x * 128, ncol = blockIdx.y * 128;

    f32x4 acc[4][4];
#pragma unroll
    for (int m = 0; m < 4; ++m)
#pragma unroll
        for (int n = 0; n < 4; ++n) acc[m][n] = (f32x4){0.f, 0.f, 0.f, 0.f};

    gemm_loop(X, WT + z * (1024 * 1024), mrow, ncol, lds_a, lds_b, acc);

    const int t = threadIdx.x, lane = t & 63, w = t >> 6;
    const int wm = (w >> 1) * 64, wn = (w & 1) * 64;
    const int l15 = lane & 15, lg = lane >> 4;
#pragma unroll
    for (int m = 0; m < 4; ++m)
#pragma unroll
        for (int n = 0; n < 4; ++n)
#pragma unroll
            for (int r = 0; r < 4; ++r) {
                int gr = mrow + wm + m * 16 + lg * 4 + r;   // b*2048 + s
                int gc = ncol + wn + n * 16 + l15;          // h*64 + d
                int b = gr >> 11, s = gr & 2047, h = gc >> 6, d = gc & 63;
                if (z == 0) {
                    qb[((b * 16 + h) * 2048 + s) * 64 + d] = f2bf(acc[m][n][r]);
                } else {
                    int idx = ((b * 16 + h) * 4096 + 2048 + s) * 64 + d;
                    if (z == 1) { kc[idx] = acc[m][n][r]; if (kb) kb[idx] = f2bf(acc[m][n][r]); }
                    else {
                        vc[idx] = acc[m][n][r];
                        if (vbn) vbn[((b * 16 + h) * 2048 + s) * 64 + d] = f2bf(acc[m][n][r]);
                    }
                }
            }
}

// ============ O projection: A bf16 x WT bf16 -> out f32 ============
__global__ __launch_bounds__(256) void k_gemm_o(const u16* A, const u16* WT, float* out) {
    __shared__ u16 lds_a[128 * 32];
    __shared__ u16 lds_b[128 * 32];
    const int mrow = blockIdx.x * 128, ncol = blockIdx.y * 128;

    f32x4 acc[4][4];
#pragma unroll
    for (int m = 0; m < 4; ++m)
#pragma unroll
        for (int n = 0; n < 4; ++n) acc[m][n] = (f32x4){0.f, 0.f, 0.f, 0.f};

    gemm_loop(A, WT, mrow, ncol, lds_a, lds_b, acc);

    const int t = threadIdx.x, lane = t & 63, w = t >> 6;
    const int wm = (w >> 1) * 64, wn = (w & 1) * 64;
    const int l15 = lane & 15, lg = lane >> 4;
#pragma unroll
    for (int m = 0; m < 4; ++m)
#pragma unroll
        for (int n = 0; n < 4; ++n)
#pragma unroll
            for (int r = 0; r < 4; ++r) {
                int gr = mrow + wm + m * 16 + lg * 4 + r;
                int gc = ncol + wn + n * 16 + l15;
                out[gr * 1024 + gc] = acc[m][n][r];
            }
}

// ============ FAST attention v7: 32x32x16 MFMA, 32 qrows/wave, 4 waves ============
// grid 512 (XCD-swizzled). QBLK=128. KV tile 64. 2-buf K/V, 1 barrier/tile.
// C/D map (m74/m101): col=lane&31, row=(reg&3)+8*(reg>>2)+4*(lane>>5).
#define LOG2E_SCALE 0.18033688f   // 0.125 * log2(e)
#define RESCALE_THR 11.0f
__global__ __launch_bounds__(256) void k_attn_d(const u16* __restrict__ qb,
                                                const u16* __restrict__ kb,
                                                const u16* __restrict__ vbT,
                                                u16* __restrict__ aws) {
    __shared__ u16 lk[2][4096];      // K tile [key][64d], chunk-swizzled (c ^= row&7)
    __shared__ u16 lv[2][4096];      // V^T tile [d][64keys], chunk-swizzled
    __shared__ u16 lp[4][2048];      // per-wave P [q 32][key 64], chunk-swizzled

    const int t = threadIdx.x, lane = t & 63, w = t >> 6;   // 4 waves
    const int l31 = lane & 31, hi = lane >> 5;
    const int n = blockIdx.x;
    const int wg = (n & 7) * 64 + (n >> 3);       // XCD bijection (512 % 8 == 0)
    const int qt = wg & 15, bh = wg >> 4;
    const int b = bh >> 4, h = bh & 15;

    const u16* Qb  = qb + (bh * 2048 + qt * 128 + w * 32) * 64;
    const u16* Kbh = kb + bh * (ST * 64);
    const u16* VbT = vbT + bh * (64 * ST);

    // staging: 256 threads x 2 16B-loads cover each 64x64 bf16 tile
    const int kr = t >> 3, kc8 = t & 7;           // kr 0..31
    const int swz8 = (kc8 ^ (kr & 7)) * 8;
    const int srcK0 = kr * 64 + swz8, srcK1 = (32 + kr) * 64 + swz8;
    const int srcV0 = kr * ST + swz8, srcV1 = (32 + kr) * ST + swz8;

    // Q B-frags: col(qrow)=l31, k(d)=slice*16 + hi*8 + j
    bf16x8 qf[4];
#pragma unroll
    for (int sl = 0; sl < 4; ++sl)
        qf[sl] = *(const bf16x8*)&Qb[l31 * 64 + sl * 16 + hi * 8];

    f32x16 oA = (f32x16)(0.f), oB = (f32x16)(0.f);   // dgroup 0 / 1
    float m_ = -INFINITY, ls = 0.f;                   // m_: wave-uniform; ls: per-lane partial

    // prologue: stage tile 0
    gload_lds16(Kbh + srcK0, &lk[0][t * 8]);
    gload_lds16(Kbh + srcK1, &lk[0][2048 + t * 8]);
    gload_lds16(VbT + srcV0, &lv[0][t * 8]);
    gload_lds16(VbT + srcV1, &lv[0][2048 + t * 8]);
    __syncthreads();

    for (int kt = 0; kt < ST / 64; ++kt) {
        const int cur = kt & 1, nxt = cur ^ 1;
        const bool more = (kt + 1 < ST / 64);
        if (more) {
            const u16* Kt = Kbh + (kt + 1) * 4096;
            gload_lds16(Kt + srcK0, &lk[nxt][t * 8]);
            gload_lds16(Kt + srcK1, &lk[nxt][2048 + t * 8]);
            const u16* Vt = VbT + (kt + 1) * 64;
            gload_lds16(Vt + srcV0, &lv[nxt][t * 8]);
            gload_lds16(Vt + srcV1, &lv[nxt][2048 + t * 8]);
        }

        // ---- S^T = K·Q^T (2 key-halves x 4 d-slices), log2 units ----
        f32x16 sA = (f32x16)(0.f), sB = (f32x16)(0.f);
        __builtin_amdgcn_s_setprio(1);
#pragma unroll
        for (int sl = 0; sl < 4; ++sl) {
            bf16x8 kf = *(const bf16x8*)&lk[cur][l31 * 64 + (((sl * 2 + hi) ^ (l31 & 7)) * 8)];
            sA = __builtin_amdgcn_mfma_f32_32x32x16_bf16(kf, qf[sl], sA, 0, 0, 0);
        }
#pragma unroll
        for (int sl = 0; sl < 4; ++sl) {
            bf16x8 kf = *(const bf16x8*)&lk[cur][(32 + l31) * 64 + (((sl * 2 + hi) ^ (l31 & 7)) * 8)];
            sB = __builtin_amdgcn_mfma_f32_32x32x16_bf16(kf, qf[sl], sB, 0, 0, 0);
        }
        __builtin_amdgcn_s_setprio(0);
        sA = sA * LOG2E_SCALE;
        sB = sB * LOG2E_SCALE;

        // ---- per-lane partial max; wave-uniform m_ (rescale is rare) ----
        float tm = sA[0];
#pragma unroll
        for (int i = 1; i < 16; ++i) tm = fmaxf(tm, sA[i]);
#pragma unroll
        for (int i = 0; i < 16; ++i) tm = fmaxf(tm, sB[i]);
        if (__any(tm > m_ + RESCALE_THR)) {
#pragma unroll
            for (int off = 1; off < 64; off <<= 1) tm = fmaxf(tm, __shfl_xor(tm, off));
            float mn = fmaxf(m_, tm);
            float corr = exp2f(m_ - mn);
            ls *= corr;
            m_ = mn;
            oA = oA * corr;
            oB = oB * corr;
        }

        // ---- P = exp2(s - m_): pack 4 keys per uint2 into swizzled lp ----
        // lane regs rq*4+i are keys ct*32 + rq*8 + hi*4 + i  (chunk = ct*4+rq)
#pragma unroll
        for (int rq = 0; rq < 4; ++rq) {
            float a0 = exp2f(sA[rq * 4 + 0] - m_), a1 = exp2f(sA[rq * 4 + 1] - m_);
            float a2 = exp2f(sA[rq * 4 + 2] - m_), a3 = exp2f(sA[rq * 4 + 3] - m_);
            ls += (a0 + a1) + (a2 + a3);
            *(uint2*)&lp[w][l31 * 64 + ((rq ^ (l31 & 7)) * 8) + hi * 4] =
                make_uint2(cvtpk(a0, a1), cvtpk(a2, a3));
            float b0 = exp2f(sB[rq * 4 + 0] - m_), b1 = exp2f(sB[rq * 4 + 1] - m_);
            float b2 = exp2f(sB[rq * 4 + 2] - m_), b3 = exp2f(sB[rq * 4 + 3] - m_);
            ls += (b0 + b1) + (b2 + b3);
            *(uint2*)&lp[w][l31 * 64 + (((4 + rq) ^ (l31 & 7)) * 8) + hi * 4] =
                make_uint2(cvtpk(b0, b1), cvtpk(b2, b3));
        }

        // ---- PV: A = P[q][k-slice] (row=l31, k=hi*8+j), B = V^T-frag ----
        bf16x8 pA[4];
#pragma unroll
        for (int ks = 0; ks < 4; ++ks)
            pA[ks] = *(const bf16x8*)&lp[w][l31 * 64 + (((ks * 2 + hi) ^ (l31 & 7)) * 8)];
        __builtin_amdgcn_s_setprio(1);
#pragma unroll
        for (int ks = 0; ks < 4; ++ks) {
            bf16x8 vf = *(const bf16x8*)&lv[cur][l31 * 64 + (((ks * 2 + hi) ^ (l31 & 7)) * 8)];
            oA = __builtin_amdgcn_mfma_f32_32x32x16_bf16(pA[ks], vf, oA, 0, 0, 0);
        }
#pragma unroll
        for (int ks = 0; ks < 4; ++ks) {
            bf16x8 vf = *(const bf16x8*)&lv[cur][(32 + l31) * 64 + (((ks * 2 + hi) ^ (l31 & 7)) * 8)];
            oB = __builtin_amdgcn_mfma_f32_32x32x16_bf16(pA[ks], vf, oB, 0, 0, 0);
        }
        __builtin_amdgcn_s_setprio(0);

        __syncthreads();   // staging(nxt) drained + all reads of cur done
    }

    // ---- epilogue: row-sum ls, per-reg normalize, store bf16 ----
    ls += __shfl_xor(ls, 32);        // lanes l31 / l31+32 hold same qrow
    const int qbase = qt * 128 + w * 32;
#pragma unroll
    for (int reg = 0; reg < 16; ++reg) {
        int q = (reg & 3) + 8 * (reg >> 2) + 4 * hi;
        float inv = 1.f / __shfl(ls, q);
        int row = (b * 2048 + qbase + q) * 1024 + h * 64;
        aws[row + l31]      = f2bf(oA[reg] * inv);
        aws[row + 32 + l31] = f2bf(oB[reg] * inv);
    }
}

// ============ FALLBACK attention (round-7 proven, f32 caches) ============
__global__ __launch_bounds__(256) void k_attn(const u16* qb, const float* kc,
                                              const float* vc, u16* aws) {
    __shared__ u16 lk[64 * 72];
    __shared__ u16 lvt[64 * 72];
    __shared__ u16 lp[4][16 * 72];

    const int t = threadIdx.x, lane = t & 63, w = t >> 6;
    const int l15 = lane & 15, lg = lane >> 4;
    const int qt = blockIdx.x;
    const int bh = blockIdx.y;
    const int b = bh >> 4, h = bh & 15;

    const u16* Qb = qb + (bh * 2048 + qt * 64 + w * 16) * 64;
    const float* Kb = kc + bh * (ST * 64);
    const float* Vb = vc + bh * (ST * 64);

    bf16x8 qf[2];
#pragma unroll
    for (int ds = 0; ds < 2; ++ds)
        qf[ds] = *(const bf16x8*)&Qb[l15 * 64 + ds * 32 + lg * 8];

    f32x4 o[4];
    float m_[4], ls[4];
#pragma unroll
    for (int i = 0; i < 4; ++i) { o[i] = (f32x4){0.f, 0.f, 0.f, 0.f}; m_[i] = -INFINITY; ls[i] = 0.f; }

    for (int kt = 0; kt < ST / 64; ++kt) {
        const float* ks = Kb + kt * 64 * 64;
        const float* vs = Vb + kt * 64 * 64;
#pragma unroll
        for (int p = 0; p < 2; ++p) {
            int r = (t >> 3) + p * 32, c8 = (t & 7) * 8;
            const float4* k4 = (const float4*)&ks[r * 64 + c8];
            *(uint4*)&lk[r * 72 + c8] = pack8(k4[0], k4[1]);
            const float4* v4 = (const float4*)&vs[r * 64 + c8];
            uint4 vv = pack8(v4[0], v4[1]);
            const u16* e = (const u16*)&vv;
#pragma unroll
            for (int j = 0; j < 8; ++j) lvt[(c8 + j) * 72 + r] = e[j];
        }
        __syncthreads();

        f32x4 s[4];
#pragma unroll
        for (int ni = 0; ni < 4; ++ni) {
            f32x4 a = (f32x4){0.f, 0.f, 0.f, 0.f};
#pragma unroll
            for (int ds = 0; ds < 2; ++ds) {
                bf16x8 kf = *(const bf16x8*)&lk[(ni * 16 + l15) * 72 + ds * 32 + lg * 8];
                a = __builtin_amdgcn_mfma_f32_16x16x32_bf16(qf[ds], kf, a, 0, 0, 0);
            }
            s[ni] = a * 0.125f;
        }

#pragma unroll
        for (int r = 0; r < 4; ++r) {
            float tm = fmaxf(fmaxf(s[0][r], s[1][r]), fmaxf(s[2][r], s[3][r]));
#pragma unroll
            for (int off = 1; off < 16; off <<= 1) tm = fmaxf(tm, __shfl_xor(tm, off));
            float mn = fmaxf(m_[r], tm);
            float corr = __expf(m_[r] - mn);
            float rs = 0.f;
#pragma unroll
            for (int ni = 0; ni < 4; ++ni) {
                float p = __expf(s[ni][r] - mn);
                s[ni][r] = p;
                rs += p;
            }
#pragma unroll
            for (int off = 1; off < 16; off <<= 1) rs += __shfl_xor(rs, off);
            ls[r] = ls[r] * corr + rs;
            m_[r] = mn;
#pragma unroll
            for (int dt = 0; dt < 4; ++dt) o[dt][r] *= corr;
        }

#pragma unroll
        for (int ni = 0; ni < 4; ++ni)
#pragma unroll
            for (int r = 0; r < 4; ++r)
                lp[w][(lg * 4 + r) * 72 + ni * 16 + l15] = f2bf(s[ni][r]);

#pragma unroll
        for (int dt = 0; dt < 4; ++dt) {
#pragma unroll
            for (int kss = 0; kss < 2; ++kss) {
                bf16x8 pf = *(const bf16x8*)&lp[w][l15 * 72 + kss * 32 + lg * 8];
                bf16x8 vf = *(const bf16x8*)&lvt[(dt * 16 + l15) * 72 + kss * 32 + lg * 8];
                o[dt] = __builtin_amdgcn_mfma_f32_16x16x32_bf16(pf, vf, o[dt], 0, 0, 0);
            }
        }
        __syncthreads();
    }

    const int qrow = qt * 64 + w * 16 + lg * 4;
#pragma unroll
    for (int r = 0; r < 4; ++r) {
        float inv = 1.f / ls[r];
#pragma unroll
        for (int dt = 0; dt < 4; ++dt) {
            int sg = qrow + r;
            int col = h * 64 + dt * 16 + l15;
            aws[(b * 2048 + sg) * 1024 + col] = f2bf(o[dt][r] * inv);
        }
    }
}

// ============ plain f32 cache copy (fallback tier) ============
__global__ __launch_bounds__(256) void k_copy_cache(const float4* __restrict__ k_in,
                                                    const float4* __restrict__ v_in,
                                                    float4* k_out, float4* v_out) {
    int t = blockIdx.x * 256 + threadIdx.x;
    int bh = t >> 15;
    int i = t & 32767;
    k_out[bh * 65536 + i] = k_in[t];
    v_out[bh * 65536 + i] = v_in[t];
}

extern "C" void kernel_launch(void* const* d_in, const int* in_sizes, int n_in,
                              void* d_out, int out_size, void* d_ws, size_t ws_size,
                              hipStream_t stream) {
    const float* x   = (const float*)d_in[0];
    const float* kvk = (const float*)d_in[1];
    const float* kvv = (const float*)d_in[2];
    const float* wq  = (const float*)d_in[3];
    const float* wk  = (const float*)d_in[4];
    const float* wv  = (const float*)d_in[5];
    const float* wo  = (const float*)d_in[6];

    float* out = (float*)d_out;                // [2,2048,1024] f32 (output 0)
    float* kc  = out + 4194304;                // [2,16,4096,64] f32 (output 1)
    float* vc  = kc + 8388608;                 // [2,16,4096,64] f32 (output 2)

    u16* qb = (u16*)d_out;                     // Q bf16 parked in out[0 : 8.39MB]
    u16* xb = (u16*)d_out + 4194304;           // x bf16 in out[8.39 : 16.78MB]

    if (ws_size >= (size_t)50331648) {
        // ws: wt(8.39) | kb(16.78) | vbT(16.78) | vbn(8.39, aliased by aws) = 50.33MB
        u16* wt  = (u16*)d_ws;
        u16* kb  = wt + 4194304;
        u16* vbT = kb + 8388608;
        u16* vbn = vbT + 8388608;
        u16* aws = vbn;                        // vbn dead after k_vt

        k_cvt_x<<<dim3(2048), dim3(256), 0, stream>>>(x, xb);
        k_transpose<<<dim3(16, 16, 4), dim3(256), 0, stream>>>(wq, wk, wv, wo, wt);
        k_copy_cache_t<<<dim3(32, 32), dim3(256), 0, stream>>>(kvk, kvv, kc, vc, kb, vbT);
        k_gemm_qkv<<<dim3(32, 8, 3), dim3(256), 0, stream>>>(xb, wt, qb, kc, vc, kb, vbn);
        k_vt<<<dim3(32, 32), dim3(256), 0, stream>>>(vbn, vbT);
        k_attn_d<<<dim3(512), dim3(256), 0, stream>>>(qb, kb, vbT, aws);
        k_gemm_o<<<dim3(32, 8), dim3(256), 0, stream>>>(aws, wt + 3 * 1048576, out);
    } else {
        // round-7 proven fallback: ws = wt(8.39) + {xb2|aws}(8.39) MB
        u16* wt  = (u16*)d_ws;
        u16* xb2 = wt + 4 * 1048576;
        u16* aws = xb2;

        k_cvt_x<<<dim3(2048), dim3(256), 0, stream>>>(x, xb2);
        k_transpose<<<dim3(16, 16, 4), dim3(256), 0, stream>>>(wq, wk, wv, wo, wt);
        k_copy_cache<<<dim3(4096), dim3(256), 0, stream>>>((const float4*)kvk, (const float4*)kvv,
                                                           (float4*)kc, (float4*)vc);
        k_gemm_qkv<<<dim3(32, 8, 3), dim3(256), 0, stream>>>(xb2, wt, qb, kc, vc, nullptr, nullptr);
        k_attn<<<dim3(32, 32), dim3(256), 0, stream>>>(qb, kc, vc, aws);
        k_gemm_o<<<dim3(32, 8), dim3(256), 0, stream>>>(aws, wt + 3 * 1048576, out);
    }
}

// Round 15
// 233.454 us; speedup vs baseline: 1.0559x; 1.0559x over previous
//
#include <hip/hip_runtime.h>
#include <hip/hip_bf16.h>

typedef unsigned int u32;
typedef unsigned short u16;
typedef __bf16 bf16x8 __attribute__((ext_vector_type(8)));
typedef float f32x4 __attribute__((ext_vector_type(4)));

typedef const __attribute__((address_space(1))) u32 gas_u32;
typedef __attribute__((address_space(3))) u32 las_u32;

#define ST 4096   // total KV length

__device__ __forceinline__ u16 f2bf(float f) {
    u32 u = __builtin_bit_cast(u32, f);
    u32 r = (u + 0x7FFFu + ((u >> 16) & 1u)) >> 16;
    return (u16)r;
}

__device__ __forceinline__ u32 cvtpk(float lo, float hi) {
    u32 r;
    asm("v_cvt_pk_bf16_f32 %0, %1, %2" : "=v"(r) : "v"(lo), "v"(hi));
    return r;
}

__device__ __forceinline__ uint4 pack8(float4 a, float4 b) {
    uint4 o;
    u16* e = (u16*)&o;
    e[0] = f2bf(a.x); e[1] = f2bf(a.y); e[2] = f2bf(a.z); e[3] = f2bf(a.w);
    e[4] = f2bf(b.x); e[5] = f2bf(b.y); e[6] = f2bf(b.z); e[7] = f2bf(b.w);
    return o;
}

__device__ __forceinline__ void gload_lds16(const u16* g, u16* l) {
    __builtin_amdgcn_global_load_lds((gas_u32*)g, (las_u32*)l, 16, 0, 0);
}

// ============ FUSED prep: x-cvt | weight-transpose | cache copy+bf16+V^T ============
// grid 4096 x 256:
//   [0,2048):    x f32 -> bf16 (8 elems/thread)
//   [2048,3072): WT[e][d] = bf16(W[d][e])  (1024 = 4 weights x 16x16 tiles)
//   [3072,4096): kv caches -> f32 halves + bf16 K + transposed bf16 V^T (32 kt x 32 bh)
__global__ __launch_bounds__(256) void k_prep(const float* __restrict__ x, u16* __restrict__ xb,
                                              const float* w0, const float* w1,
                                              const float* w2, const float* w3, u16* wt,
                                              const float* __restrict__ k_in,
                                              const float* __restrict__ v_in,
                                              float* kc, float* vc, u16* kb, u16* vbT) {
    __shared__ u16 tile[64 * 72];
    const int bid = blockIdx.x;
    const int t = threadIdx.x;

    if (bid < 2048) {
        int i = bid * 256 + t;
        const float4* s = (const float4*)(x + i * 8);
        *(uint4*)(xb + i * 8) = pack8(s[0], s[1]);
        return;
    }

    const int r = t >> 3, c8 = (t & 7) * 8;
    if (bid < 3072) {
        int idx = bid - 2048;
        int z = idx >> 8, rem = idx & 255;
        int tc = (rem & 15) * 64, tr = (rem >> 4) * 64;
        const float* W = (z == 0) ? w0 : (z == 1) ? w1 : (z == 2) ? w2 : w3;
        u16* WT = wt + z * (1024 * 1024);
#pragma unroll
        for (int p = 0; p < 2; ++p) {
            int rr = r + p * 32;
            const float4* src = (const float4*)&W[(tr + rr) * 1024 + tc + c8];
            *(uint4*)&tile[rr * 72 + c8] = pack8(src[0], src[1]);
        }
        __syncthreads();
#pragma unroll
        for (int p = 0; p < 2; ++p) {
            int rr = r + p * 32;
            uint4 vv;
            u16* e = (u16*)&vv;
#pragma unroll
            for (int j = 0; j < 8; ++j) e[j] = tile[(c8 + j) * 72 + rr];
            *(uint4*)&WT[(tc + rr) * 1024 + tr + c8] = vv;
        }
        return;
    }

    {   // cache copy: f32 old halves + bf16 K + transposed bf16 V^T
        int idx = bid - 3072;
        int kt = idx & 31, bh = idx >> 5;
#pragma unroll
        for (int p = 0; p < 2; ++p) {
            int rr = r + p * 32;
            int srow = (bh * 2048 + kt * 64 + rr) * 64 + c8;
            int drow = (bh * 4096 + kt * 64 + rr) * 64 + c8;
            const float4* ks = (const float4*)&k_in[srow];
            const float4* vs = (const float4*)&v_in[srow];
            float4 k0 = ks[0], k1 = ks[1], v0 = vs[0], v1 = vs[1];
            *(float4*)&kc[drow] = k0; *(float4*)&kc[drow + 4] = k1;
            *(float4*)&vc[drow] = v0; *(float4*)&vc[drow + 4] = v1;
            *(uint4*)&kb[drow] = pack8(k0, k1);
            *(uint4*)&tile[rr * 72 + c8] = pack8(v0, v1);
        }
        __syncthreads();
#pragma unroll
        for (int p = 0; p < 2; ++p) {
            int dd = r + p * 32;
            uint4 vv;
            u16* e = (u16*)&vv;
#pragma unroll
            for (int j = 0; j < 8; ++j) e[j] = tile[(c8 + j) * 72 + dd];
            *(uint4*)&vbT[(bh * 64 + dd) * 4096 + kt * 64 + c8] = vv;
        }
    }
}

// ============ separate kernels (fallback tier) ============
__global__ __launch_bounds__(256) void k_cvt_x(const float* __restrict__ x, u16* __restrict__ xb) {
    int t = blockIdx.x * 256 + threadIdx.x;
    const float4* s = (const float4*)(x + t * 8);
    *(uint4*)(xb + t * 8) = pack8(s[0], s[1]);
}

__global__ __launch_bounds__(256) void k_transpose(const float* w0, const float* w1,
                                                   const float* w2, const float* w3, u16* wt) {
    int z = blockIdx.z;
    const float* W = (z == 0) ? w0 : (z == 1) ? w1 : (z == 2) ? w2 : w3;
    u16* WT = wt + z * (1024 * 1024);
    __shared__ u16 tile[64 * 72];
    int t = threadIdx.x;
    int tr = blockIdx.y * 64, tc = blockIdx.x * 64;
#pragma unroll
    for (int p = 0; p < 2; ++p) {
        int r = (t >> 3) + p * 32, c8 = (t & 7) * 8;
        const float4* src = (const float4*)&W[(tr + r) * 1024 + tc + c8];
        *(uint4*)&tile[r * 72 + c8] = pack8(src[0], src[1]);
    }
    __syncthreads();
#pragma unroll
    for (int p = 0; p < 2; ++p) {
        int r = (t >> 3) + p * 32, c8 = (t & 7) * 8;
        uint4 vv;
        u16* e = (u16*)&vv;
#pragma unroll
        for (int j = 0; j < 8; ++j) e[j] = tile[(c8 + j) * 72 + r];
        *(uint4*)&WT[(tc + r) * 1024 + tr + c8] = vv;
    }
}

__global__ __launch_bounds__(256) void k_copy_cache(const float4* __restrict__ k_in,
                                                    const float4* __restrict__ v_in,
                                                    float4* k_out, float4* v_out) {
    int t = blockIdx.x * 256 + threadIdx.x;
    int bh = t >> 15;
    int i = t & 32767;
    k_out[bh * 65536 + i] = k_in[t];
    v_out[bh * 65536 + i] = v_in[t];
}

// ============ transpose new-half V rows: vbn [bh][2048][64] -> vbT cols 2048+ ============
__global__ __launch_bounds__(256) void k_vt(const u16* __restrict__ vbn, u16* __restrict__ vbT) {
    __shared__ u16 tile[64 * 72];
    const int t = threadIdx.x;
    const int kt = blockIdx.x, bh = blockIdx.y;
    const int r = t >> 3, c8 = (t & 7) * 8;
#pragma unroll
    for (int p = 0; p < 2; ++p) {
        int rr = r + p * 32;
        *(uint4*)&tile[rr * 72 + c8] =
            *(const uint4*)&vbn[(bh * 2048 + kt * 64 + rr) * 64 + c8];
    }
    __syncthreads();
#pragma unroll
    for (int p = 0; p < 2; ++p) {
        int dd = r + p * 32;
        uint4 vv;
        u16* e = (u16*)&vv;
#pragma unroll
        for (int j = 0; j < 8; ++j) e[j] = tile[(c8 + j) * 72 + dd];
        *(uint4*)&vbT[(bh * 64 + dd) * 4096 + 2048 + kt * 64 + c8] = vv;
    }
}

// ============ MFMA GEMM mainloop (m97-pattern): C(128x128) += A * BT^T ============
__device__ __forceinline__ void gemm_loop(const u16* A, const u16* BT, int mrow, int ncol,
                                          u16* lds_a, u16* lds_b, f32x4 (&acc)[4][4]) {
    const int t = threadIdx.x;
    const int lane = t & 63;
    const int w = t >> 6;
    const int wm = (w >> 1) * 64, wn = (w & 1) * 64;
    const int l15 = lane & 15, lg = lane >> 4;

    const u16* gA = A + (mrow + (t >> 2)) * 1024 + (t & 3) * 8;
    const u16* gB = BT + (ncol + (t >> 2)) * 1024 + (t & 3) * 8;
    u16* la = lds_a + t * 8;
    u16* lb = lds_b + t * 8;

    for (int k0 = 0; k0 < 1024; k0 += 32) {
        gload_lds16(gA + k0, la);
        gload_lds16(gA + k0 + 64 * 1024, la + 64 * 32);
        gload_lds16(gB + k0, lb);
        gload_lds16(gB + k0 + 64 * 1024, lb + 64 * 32);
        __syncthreads();
        bf16x8 af[4], bfr[4];
#pragma unroll
        for (int m = 0; m < 4; ++m)
            af[m] = *(const bf16x8*)&lds_a[(wm + m * 16 + l15) * 32 + lg * 8];
#pragma unroll
        for (int n = 0; n < 4; ++n)
            bfr[n] = *(const bf16x8*)&lds_b[(wn + n * 16 + l15) * 32 + lg * 8];
#pragma unroll
        for (int m = 0; m < 4; ++m)
#pragma unroll
            for (int n = 0; n < 4; ++n)
                acc[m][n] = __builtin_amdgcn_mfma_f32_16x16x32_bf16(af[m], bfr[n], acc[m][n], 0, 0, 0);
        __syncthreads();
    }
}

// ============ QKV projection with scatter ============
__global__ __launch_bounds__(256) void k_gemm_qkv(const u16* X, const u16* WT,
                                                  u16* qb, float* kc, float* vc,
                                                  u16* kb, u16* vbn) {
    __shared__ u16 lds_a[128 * 32];
    __shared__ u16 lds_b[128 * 32];
    const int z = blockIdx.z;
    const int mrow = blockIdx.x * 128, ncol = blockIdx.y * 128;

    f32x4 acc[4][4];
#pragma unroll
    for (int m = 0; m < 4; ++m)
#pragma unroll
        for (int n = 0; n < 4; ++n) acc[m][n] = (f32x4){0.f, 0.f, 0.f, 0.f};

    gemm_loop(X, WT + z * (1024 * 1024), mrow, ncol, lds_a, lds_b, acc);

    const int t = threadIdx.x, lane = t & 63, w = t >> 6;
    const int wm = (w >> 1) * 64, wn = (w & 1) * 64;
    const int l15 = lane & 15, lg = lane >> 4;
#pragma unroll
    for (int m = 0; m < 4; ++m)
#pragma unroll
        for (int n = 0; n < 4; ++n)
#pragma unroll
            for (int r = 0; r < 4; ++r) {
                int gr = mrow + wm + m * 16 + lg * 4 + r;   // b*2048 + s
                int gc = ncol + wn + n * 16 + l15;          // h*64 + d
                int b = gr >> 11, s = gr & 2047, h = gc >> 6, d = gc & 63;
                if (z == 0) {
                    qb[((b * 16 + h) * 2048 + s) * 64 + d] = f2bf(acc[m][n][r]);
                } else {
                    int idx = ((b * 16 + h) * 4096 + 2048 + s) * 64 + d;
                    if (z == 1) { kc[idx] = acc[m][n][r]; if (kb) kb[idx] = f2bf(acc[m][n][r]); }
                    else {
                        vc[idx] = acc[m][n][r];
                        if (vbn) vbn[((b * 16 + h) * 2048 + s) * 64 + d] = f2bf(acc[m][n][r]);
                    }
                }
            }
}

// ============ O projection: A bf16 x WT bf16 -> out f32 ============
__global__ __launch_bounds__(256) void k_gemm_o(const u16* A, const u16* WT, float* out) {
    __shared__ u16 lds_a[128 * 32];
    __shared__ u16 lds_b[128 * 32];
    const int mrow = blockIdx.x * 128, ncol = blockIdx.y * 128;

    f32x4 acc[4][4];
#pragma unroll
    for (int m = 0; m < 4; ++m)
#pragma unroll
        for (int n = 0; n < 4; ++n) acc[m][n] = (f32x4){0.f, 0.f, 0.f, 0.f};

    gemm_loop(A, WT, mrow, ncol, lds_a, lds_b, acc);

    const int t = threadIdx.x, lane = t & 63, w = t >> 6;
    const int wm = (w >> 1) * 64, wn = (w & 1) * 64;
    const int l15 = lane & 15, lg = lane >> 4;
#pragma unroll
    for (int m = 0; m < 4; ++m)
#pragma unroll
        for (int n = 0; n < 4; ++n)
#pragma unroll
            for (int r = 0; r < 4; ++r) {
                int gr = mrow + wm + m * 16 + lg * 4 + r;
                int gc = ncol + wn + n * 16 + l15;
                out[gr * 1024 + gc] = acc[m][n][r];
            }
}

// ============ FAST attention (round-12 proven best): 8 waves, 1 barrier/tile ============
// grid 512 (XCD-swizzled). 8 waves x 16 qrows (QBLK=128). KV tile 64, K+V dbuf.
#define LOG2E_SCALE 0.18033688f   // 0.125 * log2(e)
#define RESCALE_THR 11.0f         // log2 units; P bounded by 2^11
__global__ __launch_bounds__(512) void k_attn_c(const u16* __restrict__ qb,
                                                const u16* __restrict__ kb,
                                                const u16* __restrict__ vbT,
                                                u16* __restrict__ aws) {
    __shared__ u16 lk[2][4096];      // K tile [key][64d], source-chunk-swizzled
    __shared__ u16 lv[2][4096];      // V^T tile [d][64keys], source-chunk-swizzled
    __shared__ u16 lp[8][16 * 72];   // per-wave P [qrow][key] (wave-local, no barrier)

    const int t = threadIdx.x, lane = t & 63, w = t >> 6;
    const int l15 = lane & 15, lg = lane >> 4;
    const int n = blockIdx.x;
    const int wg = (n & 7) * 64 + (n >> 3);       // XCD bijection (512 % 8 == 0)
    const int qt = wg & 15, bh = wg >> 4;
    const int b = bh >> 4, h = bh & 15;

    const u16* Qb  = qb + (bh * 2048 + qt * 128 + w * 16) * 64;
    const u16* Kbh = kb + bh * (ST * 64);
    const u16* VbT = vbT + bh * (64 * ST);

    const int kr = t >> 3, kc8 = t & 7;           // kr 0..63
    const int swz8 = (kc8 ^ (kr & 7)) * 8;
    const int srcK = kr * 64 + swz8;
    const int srcV = kr * ST + swz8;

    bf16x8 qf[2];
#pragma unroll
    for (int ds = 0; ds < 2; ++ds)
        qf[ds] = *(const bf16x8*)&Qb[l15 * 64 + ds * 32 + lg * 8];

    f32x4 o[4];
    float m_ = -INFINITY, ls = 0.f;               // ls: per-lane partial
#pragma unroll
    for (int i = 0; i < 4; ++i) o[i] = (f32x4){0.f, 0.f, 0.f, 0.f};

    gload_lds16(Kbh + srcK, &lk[0][t * 8]);
    gload_lds16(VbT + srcV, &lv[0][t * 8]);
    __syncthreads();

    for (int kt = 0; kt < ST / 64; ++kt) {
        const int cur = kt & 1, nxt = cur ^ 1;
        const bool more = (kt + 1 < ST / 64);
        if (more) {
            gload_lds16(Kbh + (kt + 1) * 4096 + srcK, &lk[nxt][t * 8]);
            gload_lds16(VbT + (kt + 1) * 64 + srcV, &lv[nxt][t * 8]);
        }

        // ---- S^T = (K Q^T) in log2 units: lane l15 = qrow, regs hold 16 keys ----
        f32x4 s[4];
        __builtin_amdgcn_s_setprio(1);
#pragma unroll
        for (int ni = 0; ni < 4; ++ni) {
            f32x4 a = (f32x4){0.f, 0.f, 0.f, 0.f};
#pragma unroll
            for (int ds = 0; ds < 2; ++ds) {
                bf16x8 kf = *(const bf16x8*)&lk[cur][(ni * 16 + l15) * 64 + (((ds * 4 + lg) ^ (l15 & 7)) * 8)];
                a = __builtin_amdgcn_mfma_f32_16x16x32_bf16(kf, qf[ds], a, 0, 0, 0);
            }
            s[ni] = a * LOG2E_SCALE;
        }
        __builtin_amdgcn_s_setprio(0);

        // ---- per-lane partial max; cross-lane work only on rare rescale ----
        float t0 = fmaxf(fmaxf(s[0][0], s[0][1]), fmaxf(s[0][2], s[0][3]));
        float t1 = fmaxf(fmaxf(s[1][0], s[1][1]), fmaxf(s[1][2], s[1][3]));
        float t2 = fmaxf(fmaxf(s[2][0], s[2][1]), fmaxf(s[2][2], s[2][3]));
        float t3 = fmaxf(fmaxf(s[3][0], s[3][1]), fmaxf(s[3][2], s[3][3]));
        float tm = fmaxf(fmaxf(t0, t1), fmaxf(t2, t3));
        if (__any(tm > m_ + RESCALE_THR)) {
            tm = fmaxf(tm, __shfl_xor(tm, 16));
            tm = fmaxf(tm, __shfl_xor(tm, 32));
            float mn = fmaxf(m_, tm);
            float corr = exp2f(m_ - mn);
            ls *= corr;
            m_ = mn;
#pragma unroll
            for (int r = 0; r < 4; ++r) {
                float cr = __shfl(corr, lg * 4 + r);
#pragma unroll
                for (int dt = 0; dt < 4; ++dt) o[dt][r] *= cr;
            }
        }

        // ---- P = exp2(s - m_), packed bf16 to wave-local LDS; shfl-free ls ----
#pragma unroll
        for (int ni = 0; ni < 4; ++ni) {
            float p0 = exp2f(s[ni][0] - m_);
            float p1 = exp2f(s[ni][1] - m_);
            float p2 = exp2f(s[ni][2] - m_);
            float p3 = exp2f(s[ni][3] - m_);
            ls += (p0 + p1) + (p2 + p3);
            *(uint2*)&lp[w][l15 * 72 + ni * 16 + lg * 4] = make_uint2(cvtpk(p0, p1), cvtpk(p2, p3));
        }

        // ---- PV (lp wave-local: lgkmcnt ordering suffices) ----
        bf16x8 pf[2];
#pragma unroll
        for (int kss = 0; kss < 2; ++kss)
            pf[kss] = *(const bf16x8*)&lp[w][l15 * 72 + kss * 32 + lg * 8];
        __builtin_amdgcn_s_setprio(1);
#pragma unroll
        for (int dt = 0; dt < 4; ++dt) {
            const int dd = dt * 16 + l15;
#pragma unroll
            for (int kss = 0; kss < 2; ++kss) {
                bf16x8 vf = *(const bf16x8*)&lv[cur][dd * 64 + (((kss * 4 + lg) ^ (dd & 7)) * 8)];
                o[dt] = __builtin_amdgcn_mfma_f32_16x16x32_bf16(pf[kss], vf, o[dt], 0, 0, 0);
            }
        }
        __builtin_amdgcn_s_setprio(0);

        __syncthreads();   // single barrier: staging(nxt) drained + all reads of cur done
    }

    // ---- epilogue: unify ls across lg, normalize, store bf16 ----
    ls += __shfl_xor(ls, 16);
    ls += __shfl_xor(ls, 32);
    const int qrow = qt * 128 + w * 16 + lg * 4;
#pragma unroll
    for (int r = 0; r < 4; ++r) {
        float lr = __shfl(ls, lg * 4 + r);
        float inv = 1.f / lr;
#pragma unroll
        for (int dt = 0; dt < 4; ++dt) {
            int sg = qrow + r;
            int col = h * 64 + dt * 16 + l15;
            aws[(b * 2048 + sg) * 1024 + col] = f2bf(o[dt][r] * inv);
        }
    }
}

// ============ FALLBACK attention (round-7 proven, f32 caches) ============
__global__ __launch_bounds__(256) void k_attn(const u16* qb, const float* kc,
                                              const float* vc, u16* aws) {
    __shared__ u16 lk[64 * 72];
    __shared__ u16 lvt[64 * 72];
    __shared__ u16 lp[4][16 * 72];

    const int t = threadIdx.x, lane = t & 63, w = t >> 6;
    const int l15 = lane & 15, lg = lane >> 4;
    const int qt = blockIdx.x;
    const int bh = blockIdx.y;
    const int b = bh >> 4, h = bh & 15;

    const u16* Qb = qb + (bh * 2048 + qt * 64 + w * 16) * 64;
    const float* Kb = kc + bh * (ST * 64);
    const float* Vb = vc + bh * (ST * 64);

    bf16x8 qf[2];
#pragma unroll
    for (int ds = 0; ds < 2; ++ds)
        qf[ds] = *(const bf16x8*)&Qb[l15 * 64 + ds * 32 + lg * 8];

    f32x4 o[4];
    float m_[4], ls[4];
#pragma unroll
    for (int i = 0; i < 4; ++i) { o[i] = (f32x4){0.f, 0.f, 0.f, 0.f}; m_[i] = -INFINITY; ls[i] = 0.f; }

    for (int kt = 0; kt < ST / 64; ++kt) {
        const float* ks = Kb + kt * 64 * 64;
        const float* vs = Vb + kt * 64 * 64;
#pragma unroll
        for (int p = 0; p < 2; ++p) {
            int r = (t >> 3) + p * 32, c8 = (t & 7) * 8;
            const float4* k4 = (const float4*)&ks[r * 64 + c8];
            *(uint4*)&lk[r * 72 + c8] = pack8(k4[0], k4[1]);
            const float4* v4 = (const float4*)&vs[r * 64 + c8];
            uint4 vv = pack8(v4[0], v4[1]);
            const u16* e = (const u16*)&vv;
#pragma unroll
            for (int j = 0; j < 8; ++j) lvt[(c8 + j) * 72 + r] = e[j];
        }
        __syncthreads();

        f32x4 s[4];
#pragma unroll
        for (int ni = 0; ni < 4; ++ni) {
            f32x4 a = (f32x4){0.f, 0.f, 0.f, 0.f};
#pragma unroll
            for (int ds = 0; ds < 2; ++ds) {
                bf16x8 kf = *(const bf16x8*)&lk[(ni * 16 + l15) * 72 + ds * 32 + lg * 8];
                a = __builtin_amdgcn_mfma_f32_16x16x32_bf16(qf[ds], kf, a, 0, 0, 0);
            }
            s[ni] = a * 0.125f;
        }

#pragma unroll
        for (int r = 0; r < 4; ++r) {
            float tm = fmaxf(fmaxf(s[0][r], s[1][r]), fmaxf(s[2][r], s[3][r]));
#pragma unroll
            for (int off = 1; off < 16; off <<= 1) tm = fmaxf(tm, __shfl_xor(tm, off));
            float mn = fmaxf(m_[r], tm);
            float corr = __expf(m_[r] - mn);
            float rs = 0.f;
#pragma unroll
            for (int ni = 0; ni < 4; ++ni) {
                float p = __expf(s[ni][r] - mn);
                s[ni][r] = p;
                rs += p;
            }
#pragma unroll
            for (int off = 1; off < 16; off <<= 1) rs += __shfl_xor(rs, off);
            ls[r] = ls[r] * corr + rs;
            m_[r] = mn;
#pragma unroll
            for (int dt = 0; dt < 4; ++dt) o[dt][r] *= corr;
        }

#pragma unroll
        for (int ni = 0; ni < 4; ++ni)
#pragma unroll
            for (int r = 0; r < 4; ++r)
                lp[w][(lg * 4 + r) * 72 + ni * 16 + l15] = f2bf(s[ni][r]);

#pragma unroll
        for (int dt = 0; dt < 4; ++dt) {
#pragma unroll
            for (int kss = 0; kss < 2; ++kss) {
                bf16x8 pf = *(const bf16x8*)&lp[w][l15 * 72 + kss * 32 + lg * 8];
                bf16x8 vf = *(const bf16x8*)&lvt[(dt * 16 + l15) * 72 + kss * 32 + lg * 8];
                o[dt] = __builtin_amdgcn_mfma_f32_16x16x32_bf16(pf, vf, o[dt], 0, 0, 0);
            }
        }
        __syncthreads();
    }

    const int qrow = qt * 64 + w * 16 + lg * 4;
#pragma unroll
    for (int r = 0; r < 4; ++r) {
        float inv = 1.f / ls[r];
#pragma unroll
        for (int dt = 0; dt < 4; ++dt) {
            int sg = qrow + r;
            int col = h * 64 + dt * 16 + l15;
            aws[(b * 2048 + sg) * 1024 + col] = f2bf(o[dt][r] * inv);
        }
    }
}

extern "C" void kernel_launch(void* const* d_in, const int* in_sizes, int n_in,
                              void* d_out, int out_size, void* d_ws, size_t ws_size,
                              hipStream_t stream) {
    const float* x   = (const float*)d_in[0];
    const float* kvk = (const float*)d_in[1];
    const float* kvv = (const float*)d_in[2];
    const float* wq  = (const float*)d_in[3];
    const float* wk  = (const float*)d_in[4];
    const float* wv  = (const float*)d_in[5];
    const float* wo  = (const float*)d_in[6];

    float* out = (float*)d_out;                // [2,2048,1024] f32 (output 0)
    float* kc  = out + 4194304;                // [2,16,4096,64] f32 (output 1)
    float* vc  = kc + 8388608;                 // [2,16,4096,64] f32 (output 2)

    u16* qb = (u16*)d_out;                     // Q bf16 parked in out[0 : 8.39MB]
    u16* xb = (u16*)d_out + 4194304;           // x bf16 in out[8.39 : 16.78MB]

    if (ws_size >= (size_t)50331648) {
        // ws: wt(8.39) | kb(16.78) | vbT(16.78) | vbn(8.39, aliased by aws) = 50.33MB
        u16* wt  = (u16*)d_ws;
        u16* kb  = wt + 4194304;
        u16* vbT = kb + 8388608;
        u16* vbn = vbT + 8388608;
        u16* aws = vbn;                        // vbn dead after k_vt

        k_prep<<<dim3(4096), dim3(256), 0, stream>>>(x, xb, wq, wk, wv, wo, wt,
                                                     kvk, kvv, kc, vc, kb, vbT);
        k_gemm_qkv<<<dim3(32, 8, 3), dim3(256), 0, stream>>>(xb, wt, qb, kc, vc, kb, vbn);
        k_vt<<<dim3(32, 32), dim3(256), 0, stream>>>(vbn, vbT);
        k_attn_c<<<dim3(512), dim3(512), 0, stream>>>(qb, kb, vbT, aws);
        k_gemm_o<<<dim3(32, 8), dim3(256), 0, stream>>>(aws, wt + 3 * 1048576, out);
    } else {
        // round-7 proven fallback: ws = wt(8.39) + {xb2|aws}(8.39) MB
        u16* wt  = (u16*)d_ws;
        u16* xb2 = wt + 4 * 1048576;
        u16* aws = xb2;

        k_cvt_x<<<dim3(2048), dim3(256), 0, stream>>>(x, xb2);
        k_transpose<<<dim3(16, 16, 4), dim3(256), 0, stream>>>(wq, wk, wv, wo, wt);
        k_copy_cache<<<dim3(4096), dim3(256), 0, stream>>>((const float4*)kvk, (const float4*)kvv,
                                                           (float4*)kc, (float4*)vc);
        k_gemm_qkv<<<dim3(32, 8, 3), dim3(256), 0, stream>>>(xb2, wt, qb, kc, vc, nullptr, nullptr);
        k_attn<<<dim3(32, 32), dim3(256), 0, stream>>>(qb, kc, vc, aws);
        k_gemm_o<<<dim3(32, 8), dim3(256), 0, stream>>>(aws, wt + 3 * 1048576, out);
    }
}

// Round 16
// 228.777 us; speedup vs baseline: 1.0775x; 1.0204x over previous
//
#include <hip/hip_runtime.h>
#include <hip/hip_bf16.h>

typedef unsigned int u32;
typedef unsigned short u16;
typedef __bf16 bf16x8 __attribute__((ext_vector_type(8)));
typedef float f32x4 __attribute__((ext_vector_type(4)));

typedef const __attribute__((address_space(1))) u32 gas_u32;
typedef __attribute__((address_space(3))) u32 las_u32;

#define ST 4096   // total KV length

__device__ __forceinline__ u16 f2bf(float f) {
    u32 u = __builtin_bit_cast(u32, f);
    u32 r = (u + 0x7FFFu + ((u >> 16) & 1u)) >> 16;
    return (u16)r;
}

__device__ __forceinline__ u32 cvtpk(float lo, float hi) {
    u32 r;
    asm("v_cvt_pk_bf16_f32 %0, %1, %2" : "=v"(r) : "v"(lo), "v"(hi));
    return r;
}

__device__ __forceinline__ uint4 pack8(float4 a, float4 b) {
    uint4 o;
    u16* e = (u16*)&o;
    e[0] = f2bf(a.x); e[1] = f2bf(a.y); e[2] = f2bf(a.z); e[3] = f2bf(a.w);
    e[4] = f2bf(b.x); e[5] = f2bf(b.y); e[6] = f2bf(b.z); e[7] = f2bf(b.w);
    return o;
}

__device__ __forceinline__ void gload_lds16(const u16* g, u16* l) {
    __builtin_amdgcn_global_load_lds((gas_u32*)g, (las_u32*)l, 16, 0, 0);
}

// ============ FUSED prep: x-cvt | weight-transpose | cache copy+bf16+V^T ============
// grid 4096 x 256:
//   [0,2048):    x f32 -> bf16 (8 elems/thread)
//   [2048,3072): WT[e][d] = bf16(W[d][e])  (1024 = 4 weights x 16x16 tiles)
//   [3072,4096): kv caches -> f32 halves + bf16 K + transposed bf16 V^T (32 kt x 32 bh)
__global__ __launch_bounds__(256) void k_prep(const float* __restrict__ x, u16* __restrict__ xb,
                                              const float* w0, const float* w1,
                                              const float* w2, const float* w3, u16* wt,
                                              const float* __restrict__ k_in,
                                              const float* __restrict__ v_in,
                                              float* kc, float* vc, u16* kb, u16* vbT) {
    __shared__ u16 tile[64 * 72];
    const int bid = blockIdx.x;
    const int t = threadIdx.x;

    if (bid < 2048) {
        int i = bid * 256 + t;
        const float4* s = (const float4*)(x + i * 8);
        *(uint4*)(xb + i * 8) = pack8(s[0], s[1]);
        return;
    }

    const int r = t >> 3, c8 = (t & 7) * 8;
    if (bid < 3072) {
        int idx = bid - 2048;
        int z = idx >> 8, rem = idx & 255;
        int tc = (rem & 15) * 64, tr = (rem >> 4) * 64;
        const float* W = (z == 0) ? w0 : (z == 1) ? w1 : (z == 2) ? w2 : w3;
        u16* WT = wt + z * (1024 * 1024);
#pragma unroll
        for (int p = 0; p < 2; ++p) {
            int rr = r + p * 32;
            const float4* src = (const float4*)&W[(tr + rr) * 1024 + tc + c8];
            *(uint4*)&tile[rr * 72 + c8] = pack8(src[0], src[1]);
        }
        __syncthreads();
#pragma unroll
        for (int p = 0; p < 2; ++p) {
            int rr = r + p * 32;
            uint4 vv;
            u16* e = (u16*)&vv;
#pragma unroll
            for (int j = 0; j < 8; ++j) e[j] = tile[(c8 + j) * 72 + rr];
            *(uint4*)&WT[(tc + rr) * 1024 + tr + c8] = vv;
        }
        return;
    }

    {   // cache copy: f32 old halves + bf16 K + transposed bf16 V^T
        int idx = bid - 3072;
        int kt = idx & 31, bh = idx >> 5;
#pragma unroll
        for (int p = 0; p < 2; ++p) {
            int rr = r + p * 32;
            int srow = (bh * 2048 + kt * 64 + rr) * 64 + c8;
            int drow = (bh * 4096 + kt * 64 + rr) * 64 + c8;
            const float4* ks = (const float4*)&k_in[srow];
            const float4* vs = (const float4*)&v_in[srow];
            float4 k0 = ks[0], k1 = ks[1], v0 = vs[0], v1 = vs[1];
            *(float4*)&kc[drow] = k0; *(float4*)&kc[drow + 4] = k1;
            *(float4*)&vc[drow] = v0; *(float4*)&vc[drow + 4] = v1;
            *(uint4*)&kb[drow] = pack8(k0, k1);
            *(uint4*)&tile[rr * 72 + c8] = pack8(v0, v1);
        }
        __syncthreads();
#pragma unroll
        for (int p = 0; p < 2; ++p) {
            int dd = r + p * 32;
            uint4 vv;
            u16* e = (u16*)&vv;
#pragma unroll
            for (int j = 0; j < 8; ++j) e[j] = tile[(c8 + j) * 72 + dd];
            *(uint4*)&vbT[(bh * 64 + dd) * 4096 + kt * 64 + c8] = vv;
        }
    }
}

// ============ separate kernels (fallback tier) ============
__global__ __launch_bounds__(256) void k_cvt_x(const float* __restrict__ x, u16* __restrict__ xb) {
    int t = blockIdx.x * 256 + threadIdx.x;
    const float4* s = (const float4*)(x + t * 8);
    *(uint4*)(xb + t * 8) = pack8(s[0], s[1]);
}

__global__ __launch_bounds__(256) void k_transpose(const float* w0, const float* w1,
                                                   const float* w2, const float* w3, u16* wt) {
    int z = blockIdx.z;
    const float* W = (z == 0) ? w0 : (z == 1) ? w1 : (z == 2) ? w2 : w3;
    u16* WT = wt + z * (1024 * 1024);
    __shared__ u16 tile[64 * 72];
    int t = threadIdx.x;
    int tr = blockIdx.y * 64, tc = blockIdx.x * 64;
#pragma unroll
    for (int p = 0; p < 2; ++p) {
        int r = (t >> 3) + p * 32, c8 = (t & 7) * 8;
        const float4* src = (const float4*)&W[(tr + r) * 1024 + tc + c8];
        *(uint4*)&tile[r * 72 + c8] = pack8(src[0], src[1]);
    }
    __syncthreads();
#pragma unroll
    for (int p = 0; p < 2; ++p) {
        int r = (t >> 3) + p * 32, c8 = (t & 7) * 8;
        uint4 vv;
        u16* e = (u16*)&vv;
#pragma unroll
        for (int j = 0; j < 8; ++j) e[j] = tile[(c8 + j) * 72 + r];
        *(uint4*)&WT[(tc + r) * 1024 + tr + c8] = vv;
    }
}

__global__ __launch_bounds__(256) void k_copy_cache(const float4* __restrict__ k_in,
                                                    const float4* __restrict__ v_in,
                                                    float4* k_out, float4* v_out) {
    int t = blockIdx.x * 256 + threadIdx.x;
    int bh = t >> 15;
    int i = t & 32767;
    k_out[bh * 65536 + i] = k_in[t];
    v_out[bh * 65536 + i] = v_in[t];
}

// ============ MFMA GEMM mainloop (m97-pattern): C(128x128) += A * BT^T ============
__device__ __forceinline__ void gemm_loop(const u16* A, const u16* BT, int mrow, int ncol,
                                          u16* lds_a, u16* lds_b, f32x4 (&acc)[4][4]) {
    const int t = threadIdx.x;
    const int lane = t & 63;
    const int w = t >> 6;
    const int wm = (w >> 1) * 64, wn = (w & 1) * 64;
    const int l15 = lane & 15, lg = lane >> 4;

    const u16* gA = A + (mrow + (t >> 2)) * 1024 + (t & 3) * 8;
    const u16* gB = BT + (ncol + (t >> 2)) * 1024 + (t & 3) * 8;
    u16* la = lds_a + t * 8;
    u16* lb = lds_b + t * 8;

    for (int k0 = 0; k0 < 1024; k0 += 32) {
        gload_lds16(gA + k0, la);
        gload_lds16(gA + k0 + 64 * 1024, la + 64 * 32);
        gload_lds16(gB + k0, lb);
        gload_lds16(gB + k0 + 64 * 1024, lb + 64 * 32);
        __syncthreads();
        bf16x8 af[4], bfr[4];
#pragma unroll
        for (int m = 0; m < 4; ++m)
            af[m] = *(const bf16x8*)&lds_a[(wm + m * 16 + l15) * 32 + lg * 8];
#pragma unroll
        for (int n = 0; n < 4; ++n)
            bfr[n] = *(const bf16x8*)&lds_b[(wn + n * 16 + l15) * 32 + lg * 8];
#pragma unroll
        for (int m = 0; m < 4; ++m)
#pragma unroll
            for (int n = 0; n < 4; ++n)
                acc[m][n] = __builtin_amdgcn_mfma_f32_16x16x32_bf16(af[m], bfr[n], acc[m][n], 0, 0, 0);
        __syncthreads();
    }
}

// ============ QKV projection with scatter (+ fused V^T transpose for z==2) ============
// smem overlay: [0,8192) lds_a | [8192,16384) lds_b during loop; reused as
// 128x136 transpose tile (17408 u16) in the z==2 epilogue.
__global__ __launch_bounds__(256) void k_gemm_qkv(const u16* X, const u16* WT,
                                                  u16* qb, float* kc, float* vc,
                                                  u16* kb, u16* vbT) {
    __shared__ u16 smem[128 * 136];
    const int z = blockIdx.z;
    const int mrow = blockIdx.x * 128, ncol = blockIdx.y * 128;

    f32x4 acc[4][4];
#pragma unroll
    for (int m = 0; m < 4; ++m)
#pragma unroll
        for (int n = 0; n < 4; ++n) acc[m][n] = (f32x4){0.f, 0.f, 0.f, 0.f};

    gemm_loop(X, WT + z * (1024 * 1024), mrow, ncol, smem, smem + 8192, acc);

    const int t = threadIdx.x, lane = t & 63, w = t >> 6;
    const int wm = (w >> 1) * 64, wn = (w & 1) * 64;
    const int l15 = lane & 15, lg = lane >> 4;
#pragma unroll
    for (int m = 0; m < 4; ++m)
#pragma unroll
        for (int n = 0; n < 4; ++n)
#pragma unroll
            for (int r = 0; r < 4; ++r) {
                int gr = mrow + wm + m * 16 + lg * 4 + r;   // b*2048 + s
                int gc = ncol + wn + n * 16 + l15;          // h*64 + d
                int b = gr >> 11, s = gr & 2047, h = gc >> 6, d = gc & 63;
                if (z == 0) {
                    qb[((b * 16 + h) * 2048 + s) * 64 + d] = f2bf(acc[m][n][r]);
                } else {
                    int idx = ((b * 16 + h) * 4096 + 2048 + s) * 64 + d;
                    if (z == 1) { kc[idx] = acc[m][n][r]; if (kb) kb[idx] = f2bf(acc[m][n][r]); }
                    else         vc[idx] = acc[m][n][r];
                }
            }

    // ---- fused V^T: stage bf16 into smem[col][row], write vbT rows ----
    if (z == 2 && vbT) {
        // gemm_loop's final __syncthreads guarantees smem reads are done
#pragma unroll
        for (int m = 0; m < 4; ++m)
#pragma unroll
            for (int n = 0; n < 4; ++n)
#pragma unroll
                for (int r = 0; r < 4; ++r)
                    smem[(wn + n * 16 + l15) * 136 + wm + m * 16 + lg * 4 + r] =
                        f2bf(acc[m][n][r]);
        __syncthreads();
        const int c = t >> 1, half = t & 1;            // col (h,d local), row-half
        const int gc = ncol + c, h2 = gc >> 6, d2 = gc & 63;
        const int bb = mrow >> 11, sbase = mrow & 2047;
        u16* dst = vbT + (size_t)((bb * 16 + h2) * 64 + d2) * 4096 + 2048 + sbase + half * 64;
        const u16* srcp = &smem[c * 136 + half * 64];
#pragma unroll
        for (int j = 0; j < 8; ++j)
            ((uint4*)dst)[j] = *(const uint4*)&srcp[j * 8];
    }
}

// ============ O projection: A bf16 x WT bf16 -> out f32 ============
__global__ __launch_bounds__(256) void k_gemm_o(const u16* A, const u16* WT, float* out) {
    __shared__ u16 lds_a[128 * 32];
    __shared__ u16 lds_b[128 * 32];
    const int mrow = blockIdx.x * 128, ncol = blockIdx.y * 128;

    f32x4 acc[4][4];
#pragma unroll
    for (int m = 0; m < 4; ++m)
#pragma unroll
        for (int n = 0; n < 4; ++n) acc[m][n] = (f32x4){0.f, 0.f, 0.f, 0.f};

    gemm_loop(A, WT, mrow, ncol, lds_a, lds_b, acc);

    const int t = threadIdx.x, lane = t & 63, w = t >> 6;
    const int wm = (w >> 1) * 64, wn = (w & 1) * 64;
    const int l15 = lane & 15, lg = lane >> 4;
#pragma unroll
    for (int m = 0; m < 4; ++m)
#pragma unroll
        for (int n = 0; n < 4; ++n)
#pragma unroll
            for (int r = 0; r < 4; ++r) {
                int gr = mrow + wm + m * 16 + lg * 4 + r;
                int gc = ncol + wn + n * 16 + l15;
                out[gr * 1024 + gc] = acc[m][n][r];
            }
}

// ============ FAST attention (round-12 proven best): 8 waves, 1 barrier/tile ============
// grid 512 (XCD-swizzled). 8 waves x 16 qrows (QBLK=128). KV tile 64, K+V dbuf.
#define LOG2E_SCALE 0.18033688f   // 0.125 * log2(e)
#define RESCALE_THR 11.0f         // log2 units; P bounded by 2^11
__global__ __launch_bounds__(512) void k_attn_c(const u16* __restrict__ qb,
                                                const u16* __restrict__ kb,
                                                const u16* __restrict__ vbT,
                                                u16* __restrict__ aws) {
    __shared__ u16 lk[2][4096];      // K tile [key][64d], source-chunk-swizzled
    __shared__ u16 lv[2][4096];      // V^T tile [d][64keys], source-chunk-swizzled
    __shared__ u16 lp[8][16 * 72];   // per-wave P [qrow][key] (wave-local, no barrier)

    const int t = threadIdx.x, lane = t & 63, w = t >> 6;
    const int l15 = lane & 15, lg = lane >> 4;
    const int n = blockIdx.x;
    const int wg = (n & 7) * 64 + (n >> 3);       // XCD bijection (512 % 8 == 0)
    const int qt = wg & 15, bh = wg >> 4;
    const int b = bh >> 4, h = bh & 15;

    const u16* Qb  = qb + (bh * 2048 + qt * 128 + w * 16) * 64;
    const u16* Kbh = kb + bh * (ST * 64);
    const u16* VbT = vbT + bh * (64 * ST);

    const int kr = t >> 3, kc8 = t & 7;           // kr 0..63
    const int swz8 = (kc8 ^ (kr & 7)) * 8;
    const int srcK = kr * 64 + swz8;
    const int srcV = kr * ST + swz8;

    bf16x8 qf[2];
#pragma unroll
    for (int ds = 0; ds < 2; ++ds)
        qf[ds] = *(const bf16x8*)&Qb[l15 * 64 + ds * 32 + lg * 8];

    f32x4 o[4];
    float m_ = -INFINITY, ls = 0.f;               // ls: per-lane partial
#pragma unroll
    for (int i = 0; i < 4; ++i) o[i] = (f32x4){0.f, 0.f, 0.f, 0.f};

    gload_lds16(Kbh + srcK, &lk[0][t * 8]);
    gload_lds16(VbT + srcV, &lv[0][t * 8]);
    __syncthreads();

    for (int kt = 0; kt < ST / 64; ++kt) {
        const int cur = kt & 1, nxt = cur ^ 1;
        const bool more = (kt + 1 < ST / 64);
        if (more) {
            gload_lds16(Kbh + (kt + 1) * 4096 + srcK, &lk[nxt][t * 8]);
            gload_lds16(VbT + (kt + 1) * 64 + srcV, &lv[nxt][t * 8]);
        }

        // ---- S^T = (K Q^T) in log2 units: lane l15 = qrow, regs hold 16 keys ----
        f32x4 s[4];
        __builtin_amdgcn_s_setprio(1);
#pragma unroll
        for (int ni = 0; ni < 4; ++ni) {
            f32x4 a = (f32x4){0.f, 0.f, 0.f, 0.f};
#pragma unroll
            for (int ds = 0; ds < 2; ++ds) {
                bf16x8 kf = *(const bf16x8*)&lk[cur][(ni * 16 + l15) * 64 + (((ds * 4 + lg) ^ (l15 & 7)) * 8)];
                a = __builtin_amdgcn_mfma_f32_16x16x32_bf16(kf, qf[ds], a, 0, 0, 0);
            }
            s[ni] = a * LOG2E_SCALE;
        }
        __builtin_amdgcn_s_setprio(0);

        // ---- per-lane partial max; cross-lane work only on rare rescale ----
        float t0 = fmaxf(fmaxf(s[0][0], s[0][1]), fmaxf(s[0][2], s[0][3]));
        float t1 = fmaxf(fmaxf(s[1][0], s[1][1]), fmaxf(s[1][2], s[1][3]));
        float t2 = fmaxf(fmaxf(s[2][0], s[2][1]), fmaxf(s[2][2], s[2][3]));
        float t3 = fmaxf(fmaxf(s[3][0], s[3][1]), fmaxf(s[3][2], s[3][3]));
        float tm = fmaxf(fmaxf(t0, t1), fmaxf(t2, t3));
        if (__any(tm > m_ + RESCALE_THR)) {
            tm = fmaxf(tm, __shfl_xor(tm, 16));
            tm = fmaxf(tm, __shfl_xor(tm, 32));
            float mn = fmaxf(m_, tm);
            float corr = exp2f(m_ - mn);
            ls *= corr;
            m_ = mn;
#pragma unroll
            for (int r = 0; r < 4; ++r) {
                float cr = __shfl(corr, lg * 4 + r);
#pragma unroll
                for (int dt = 0; dt < 4; ++dt) o[dt][r] *= cr;
            }
        }

        // ---- P = exp2(s - m_), packed bf16 to wave-local LDS; shfl-free ls ----
#pragma unroll
        for (int ni = 0; ni < 4; ++ni) {
            float p0 = exp2f(s[ni][0] - m_);
            float p1 = exp2f(s[ni][1] - m_);
            float p2 = exp2f(s[ni][2] - m_);
            float p3 = exp2f(s[ni][3] - m_);
            ls += (p0 + p1) + (p2 + p3);
            *(uint2*)&lp[w][l15 * 72 + ni * 16 + lg * 4] = make_uint2(cvtpk(p0, p1), cvtpk(p2, p3));
        }

        // ---- PV (lp wave-local: lgkmcnt ordering suffices) ----
        bf16x8 pf[2];
#pragma unroll
        for (int kss = 0; kss < 2; ++kss)
            pf[kss] = *(const bf16x8*)&lp[w][l15 * 72 + kss * 32 + lg * 8];
        __builtin_amdgcn_s_setprio(1);
#pragma unroll
        for (int dt = 0; dt < 4; ++dt) {
            const int dd = dt * 16 + l15;
#pragma unroll
            for (int kss = 0; kss < 2; ++kss) {
                bf16x8 vf = *(const bf16x8*)&lv[cur][dd * 64 + (((kss * 4 + lg) ^ (dd & 7)) * 8)];
                o[dt] = __builtin_amdgcn_mfma_f32_16x16x32_bf16(pf[kss], vf, o[dt], 0, 0, 0);
            }
        }
        __builtin_amdgcn_s_setprio(0);

        __syncthreads();   // single barrier: staging(nxt) drained + all reads of cur done
    }

    // ---- epilogue: unify ls across lg, normalize, store bf16 ----
    ls += __shfl_xor(ls, 16);
    ls += __shfl_xor(ls, 32);
    const int qrow = qt * 128 + w * 16 + lg * 4;
#pragma unroll
    for (int r = 0; r < 4; ++r) {
        float lr = __shfl(ls, lg * 4 + r);
        float inv = 1.f / lr;
#pragma unroll
        for (int dt = 0; dt < 4; ++dt) {
            int sg = qrow + r;
            int col = h * 64 + dt * 16 + l15;
            aws[(b * 2048 + sg) * 1024 + col] = f2bf(o[dt][r] * inv);
        }
    }
}

// ============ FALLBACK attention (round-7 proven, f32 caches) ============
__global__ __launch_bounds__(256) void k_attn(const u16* qb, const float* kc,
                                              const float* vc, u16* aws) {
    __shared__ u16 lk[64 * 72];
    __shared__ u16 lvt[64 * 72];
    __shared__ u16 lp[4][16 * 72];

    const int t = threadIdx.x, lane = t & 63, w = t >> 6;
    const int l15 = lane & 15, lg = lane >> 4;
    const int qt = blockIdx.x;
    const int bh = blockIdx.y;
    const int b = bh >> 4, h = bh & 15;

    const u16* Qb = qb + (bh * 2048 + qt * 64 + w * 16) * 64;
    const float* Kb = kc + bh * (ST * 64);
    const float* Vb = vc + bh * (ST * 64);

    bf16x8 qf[2];
#pragma unroll
    for (int ds = 0; ds < 2; ++ds)
        qf[ds] = *(const bf16x8*)&Qb[l15 * 64 + ds * 32 + lg * 8];

    f32x4 o[4];
    float m_[4], ls[4];
#pragma unroll
    for (int i = 0; i < 4; ++i) { o[i] = (f32x4){0.f, 0.f, 0.f, 0.f}; m_[i] = -INFINITY; ls[i] = 0.f; }

    for (int kt = 0; kt < ST / 64; ++kt) {
        const float* ks = Kb + kt * 64 * 64;
        const float* vs = Vb + kt * 64 * 64;
#pragma unroll
        for (int p = 0; p < 2; ++p) {
            int r = (t >> 3) + p * 32, c8 = (t & 7) * 8;
            const float4* k4 = (const float4*)&ks[r * 64 + c8];
            *(uint4*)&lk[r * 72 + c8] = pack8(k4[0], k4[1]);
            const float4* v4 = (const float4*)&vs[r * 64 + c8];
            uint4 vv = pack8(v4[0], v4[1]);
            const u16* e = (const u16*)&vv;
#pragma unroll
            for (int j = 0; j < 8; ++j) lvt[(c8 + j) * 72 + r] = e[j];
        }
        __syncthreads();

        f32x4 s[4];
#pragma unroll
        for (int ni = 0; ni < 4; ++ni) {
            f32x4 a = (f32x4){0.f, 0.f, 0.f, 0.f};
#pragma unroll
            for (int ds = 0; ds < 2; ++ds) {
                bf16x8 kf = *(const bf16x8*)&lk[(ni * 16 + l15) * 72 + ds * 32 + lg * 8];
                a = __builtin_amdgcn_mfma_f32_16x16x32_bf16(qf[ds], kf, a, 0, 0, 0);
            }
            s[ni] = a * 0.125f;
        }

#pragma unroll
        for (int r = 0; r < 4; ++r) {
            float tm = fmaxf(fmaxf(s[0][r], s[1][r]), fmaxf(s[2][r], s[3][r]));
#pragma unroll
            for (int off = 1; off < 16; off <<= 1) tm = fmaxf(tm, __shfl_xor(tm, off));
            float mn = fmaxf(m_[r], tm);
            float corr = __expf(m_[r] - mn);
            float rs = 0.f;
#pragma unroll
            for (int ni = 0; ni < 4; ++ni) {
                float p = __expf(s[ni][r] - mn);
                s[ni][r] = p;
                rs += p;
            }
#pragma unroll
            for (int off = 1; off < 16; off <<= 1) rs += __shfl_xor(rs, off);
            ls[r] = ls[r] * corr + rs;
            m_[r] = mn;
#pragma unroll
            for (int dt = 0; dt < 4; ++dt) o[dt][r] *= corr;
        }

#pragma unroll
        for (int ni = 0; ni < 4; ++ni)
#pragma unroll
            for (int r = 0; r < 4; ++r)
                lp[w][(lg * 4 + r) * 72 + ni * 16 + l15] = f2bf(s[ni][r]);

#pragma unroll
        for (int dt = 0; dt < 4; ++dt) {
#pragma unroll
            for (int kss = 0; kss < 2; ++kss) {
                bf16x8 pf = *(const bf16x8*)&lp[w][l15 * 72 + kss * 32 + lg * 8];
                bf16x8 vf = *(const bf16x8*)&lvt[(dt * 16 + l15) * 72 + kss * 32 + lg * 8];
                o[dt] = __builtin_amdgcn_mfma_f32_16x16x32_bf16(pf, vf, o[dt], 0, 0, 0);
            }
        }
        __syncthreads();
    }

    const int qrow = qt * 64 + w * 16 + lg * 4;
#pragma unroll
    for (int r = 0; r < 4; ++r) {
        float inv = 1.f / ls[r];
#pragma unroll
        for (int dt = 0; dt < 4; ++dt) {
            int sg = qrow + r;
            int col = h * 64 + dt * 16 + l15;
            aws[(b * 2048 + sg) * 1024 + col] = f2bf(o[dt][r] * inv);
        }
    }
}

extern "C" void kernel_launch(void* const* d_in, const int* in_sizes, int n_in,
                              void* d_out, int out_size, void* d_ws, size_t ws_size,
                              hipStream_t stream) {
    const float* x   = (const float*)d_in[0];
    const float* kvk = (const float*)d_in[1];
    const float* kvv = (const float*)d_in[2];
    const float* wq  = (const float*)d_in[3];
    const float* wk  = (const float*)d_in[4];
    const float* wv  = (const float*)d_in[5];
    const float* wo  = (const float*)d_in[6];

    float* out = (float*)d_out;                // [2,2048,1024] f32 (output 0)
    float* kc  = out + 4194304;                // [2,16,4096,64] f32 (output 1)
    float* vc  = kc + 8388608;                 // [2,16,4096,64] f32 (output 2)

    u16* qb = (u16*)d_out;                     // Q bf16 parked in out[0 : 8.39MB]
    u16* xb = (u16*)d_out + 4194304;           // x bf16 in out[8.39 : 16.78MB]

    if (ws_size >= (size_t)50331648) {
        // ws: wt(8.39) | kb(16.78) | vbT(16.78) | aws(8.39) = 50.33MB
        u16* wt  = (u16*)d_ws;
        u16* kb  = wt + 4194304;
        u16* vbT = kb + 8388608;
        u16* aws = vbT + 8388608;

        k_prep<<<dim3(4096), dim3(256), 0, stream>>>(x, xb, wq, wk, wv, wo, wt,
                                                     kvk, kvv, kc, vc, kb, vbT);
        k_gemm_qkv<<<dim3(32, 8, 3), dim3(256), 0, stream>>>(xb, wt, qb, kc, vc, kb, vbT);
        k_attn_c<<<dim3(512), dim3(512), 0, stream>>>(qb, kb, vbT, aws);
        k_gemm_o<<<dim3(32, 8), dim3(256), 0, stream>>>(aws, wt + 3 * 1048576, out);
    } else {
        // round-7 proven fallback: ws = wt(8.39) + {xb2|aws}(8.39) MB
        u16* wt  = (u16*)d_ws;
        u16* xb2 = wt + 4 * 1048576;
        u16* aws = xb2;

        k_cvt_x<<<dim3(2048), dim3(256), 0, stream>>>(x, xb2);
        k_transpose<<<dim3(16, 16, 4), dim3(256), 0, stream>>>(wq, wk, wv, wo, wt);
        k_copy_cache<<<dim3(4096), dim3(256), 0, stream>>>((const float4*)kvk, (const float4*)kvv,
                                                           (float4*)kc, (float4*)vc);
        k_gemm_qkv<<<dim3(32, 8, 3), dim3(256), 0, stream>>>(xb2, wt, qb, kc, vc, nullptr, nullptr);
        k_attn<<<dim3(32, 32), dim3(256), 0, stream>>>(qb, kc, vc, aws);
        k_gemm_o<<<dim3(32, 8), dim3(256), 0, stream>>>(aws, wt + 3 * 1048576, out);
    }
}

// Round 17
// 226.458 us; speedup vs baseline: 1.0885x; 1.0102x over previous
//
#include <hip/hip_runtime.h>
#include <hip/hip_bf16.h>

typedef unsigned int u32;
typedef unsigned short u16;
typedef __bf16 bf16x8 __attribute__((ext_vector_type(8)));
typedef float f32x4 __attribute__((ext_vector_type(4)));

typedef const __attribute__((address_space(1))) u32 gas_u32;
typedef __attribute__((address_space(3))) u32 las_u32;

#define ST 4096   // total KV length

__device__ __forceinline__ u16 f2bf(float f) {
    u32 u = __builtin_bit_cast(u32, f);
    u32 r = (u + 0x7FFFu + ((u >> 16) & 1u)) >> 16;
    return (u16)r;
}

__device__ __forceinline__ u32 cvtpk(float lo, float hi) {
    u32 r;
    asm("v_cvt_pk_bf16_f32 %0, %1, %2" : "=v"(r) : "v"(lo), "v"(hi));
    return r;
}

__device__ __forceinline__ uint4 pack8(float4 a, float4 b) {
    uint4 o;
    u16* e = (u16*)&o;
    e[0] = f2bf(a.x); e[1] = f2bf(a.y); e[2] = f2bf(a.z); e[3] = f2bf(a.w);
    e[4] = f2bf(b.x); e[5] = f2bf(b.y); e[6] = f2bf(b.z); e[7] = f2bf(b.w);
    return o;
}

__device__ __forceinline__ void gload_lds16(const u16* g, u16* l) {
    __builtin_amdgcn_global_load_lds((gas_u32*)g, (las_u32*)l, 16, 0, 0);
}

// ============ FUSED prep: x-cvt | weight-transpose | cache copy+bf16+V^T ============
__global__ __launch_bounds__(256) void k_prep(const float* __restrict__ x, u16* __restrict__ xb,
                                              const float* w0, const float* w1,
                                              const float* w2, const float* w3, u16* wt,
                                              const float* __restrict__ k_in,
                                              const float* __restrict__ v_in,
                                              float* kc, float* vc, u16* kb, u16* vbT) {
    __shared__ u16 tile[64 * 72];
    const int bid = blockIdx.x;
    const int t = threadIdx.x;

    if (bid < 2048) {
        int i = bid * 256 + t;
        const float4* s = (const float4*)(x + i * 8);
        *(uint4*)(xb + i * 8) = pack8(s[0], s[1]);
        return;
    }

    const int r = t >> 3, c8 = (t & 7) * 8;
    if (bid < 3072) {
        int idx = bid - 2048;
        int z = idx >> 8, rem = idx & 255;
        int tc = (rem & 15) * 64, tr = (rem >> 4) * 64;
        const float* W = (z == 0) ? w0 : (z == 1) ? w1 : (z == 2) ? w2 : w3;
        u16* WT = wt + z * (1024 * 1024);
#pragma unroll
        for (int p = 0; p < 2; ++p) {
            int rr = r + p * 32;
            const float4* src = (const float4*)&W[(tr + rr) * 1024 + tc + c8];
            *(uint4*)&tile[rr * 72 + c8] = pack8(src[0], src[1]);
        }
        __syncthreads();
#pragma unroll
        for (int p = 0; p < 2; ++p) {
            int rr = r + p * 32;
            uint4 vv;
            u16* e = (u16*)&vv;
#pragma unroll
            for (int j = 0; j < 8; ++j) e[j] = tile[(c8 + j) * 72 + rr];
            *(uint4*)&WT[(tc + rr) * 1024 + tr + c8] = vv;
        }
        return;
    }

    {
        int idx = bid - 3072;
        int kt = idx & 31, bh = idx >> 5;
#pragma unroll
        for (int p = 0; p < 2; ++p) {
            int rr = r + p * 32;
            int srow = (bh * 2048 + kt * 64 + rr) * 64 + c8;
            int drow = (bh * 4096 + kt * 64 + rr) * 64 + c8;
            const float4* ks = (const float4*)&k_in[srow];
            const float4* vs = (const float4*)&v_in[srow];
            float4 k0 = ks[0], k1 = ks[1], v0 = vs[0], v1 = vs[1];
            *(float4*)&kc[drow] = k0; *(float4*)&kc[drow + 4] = k1;
            *(float4*)&vc[drow] = v0; *(float4*)&vc[drow + 4] = v1;
            *(uint4*)&kb[drow] = pack8(k0, k1);
            *(uint4*)&tile[rr * 72 + c8] = pack8(v0, v1);
        }
        __syncthreads();
#pragma unroll
        for (int p = 0; p < 2; ++p) {
            int dd = r + p * 32;
            uint4 vv;
            u16* e = (u16*)&vv;
#pragma unroll
            for (int j = 0; j < 8; ++j) e[j] = tile[(c8 + j) * 72 + dd];
            *(uint4*)&vbT[(bh * 64 + dd) * 4096 + kt * 64 + c8] = vv;
        }
    }
}

// ============ separate kernels (fallback tier) ============
__global__ __launch_bounds__(256) void k_cvt_x(const float* __restrict__ x, u16* __restrict__ xb) {
    int t = blockIdx.x * 256 + threadIdx.x;
    const float4* s = (const float4*)(x + t * 8);
    *(uint4*)(xb + t * 8) = pack8(s[0], s[1]);
}

__global__ __launch_bounds__(256) void k_transpose(const float* w0, const float* w1,
                                                   const float* w2, const float* w3, u16* wt) {
    int z = blockIdx.z;
    const float* W = (z == 0) ? w0 : (z == 1) ? w1 : (z == 2) ? w2 : w3;
    u16* WT = wt + z * (1024 * 1024);
    __shared__ u16 tile[64 * 72];
    int t = threadIdx.x;
    int tr = blockIdx.y * 64, tc = blockIdx.x * 64;
#pragma unroll
    for (int p = 0; p < 2; ++p) {
        int r = (t >> 3) + p * 32, c8 = (t & 7) * 8;
        const float4* src = (const float4*)&W[(tr + r) * 1024 + tc + c8];
        *(uint4*)&tile[r * 72 + c8] = pack8(src[0], src[1]);
    }
    __syncthreads();
#pragma unroll
    for (int p = 0; p < 2; ++p) {
        int r = (t >> 3) + p * 32, c8 = (t & 7) * 8;
        uint4 vv;
        u16* e = (u16*)&vv;
#pragma unroll
        for (int j = 0; j < 8; ++j) e[j] = tile[(c8 + j) * 72 + r];
        *(uint4*)&WT[(tc + r) * 1024 + tr + c8] = vv;
    }
}

__global__ __launch_bounds__(256) void k_copy_cache(const float4* __restrict__ k_in,
                                                    const float4* __restrict__ v_in,
                                                    float4* k_out, float4* v_out) {
    int t = blockIdx.x * 256 + threadIdx.x;
    int bh = t >> 15;
    int i = t & 32767;
    k_out[bh * 65536 + i] = k_in[t];
    v_out[bh * 65536 + i] = v_in[t];
}

// ============ MFMA GEMM mainloop (m97-pattern): C(128x128) += A * BT^T ============
__device__ __forceinline__ void gemm_loop(const u16* A, const u16* BT, int mrow, int ncol,
                                          u16* lds_a, u16* lds_b, f32x4 (&acc)[4][4]) {
    const int t = threadIdx.x;
    const int lane = t & 63;
    const int w = t >> 6;
    const int wm = (w >> 1) * 64, wn = (w & 1) * 64;
    const int l15 = lane & 15, lg = lane >> 4;

    const u16* gA = A + (mrow + (t >> 2)) * 1024 + (t & 3) * 8;
    const u16* gB = BT + (ncol + (t >> 2)) * 1024 + (t & 3) * 8;
    u16* la = lds_a + t * 8;
    u16* lb = lds_b + t * 8;

    for (int k0 = 0; k0 < 1024; k0 += 32) {
        gload_lds16(gA + k0, la);
        gload_lds16(gA + k0 + 64 * 1024, la + 64 * 32);
        gload_lds16(gB + k0, lb);
        gload_lds16(gB + k0 + 64 * 1024, lb + 64 * 32);
        __syncthreads();
        bf16x8 af[4], bfr[4];
#pragma unroll
        for (int m = 0; m < 4; ++m)
            af[m] = *(const bf16x8*)&lds_a[(wm + m * 16 + l15) * 32 + lg * 8];
#pragma unroll
        for (int n = 0; n < 4; ++n)
            bfr[n] = *(const bf16x8*)&lds_b[(wn + n * 16 + l15) * 32 + lg * 8];
#pragma unroll
        for (int m = 0; m < 4; ++m)
#pragma unroll
            for (int n = 0; n < 4; ++n)
                acc[m][n] = __builtin_amdgcn_mfma_f32_16x16x32_bf16(af[m], bfr[n], acc[m][n], 0, 0, 0);
        __syncthreads();
    }
}

// ============ QKV projection with scatter (+ fused V^T transpose for z==2) ============
__global__ __launch_bounds__(256) void k_gemm_qkv(const u16* X, const u16* WT,
                                                  u16* qb, float* kc, float* vc,
                                                  u16* kb, u16* vbT) {
    __shared__ u16 smem[128 * 136];
    const int z = blockIdx.z;
    const int mrow = blockIdx.x * 128, ncol = blockIdx.y * 128;

    f32x4 acc[4][4];
#pragma unroll
    for (int m = 0; m < 4; ++m)
#pragma unroll
        for (int n = 0; n < 4; ++n) acc[m][n] = (f32x4){0.f, 0.f, 0.f, 0.f};

    gemm_loop(X, WT + z * (1024 * 1024), mrow, ncol, smem, smem + 8192, acc);

    const int t = threadIdx.x, lane = t & 63, w = t >> 6;
    const int wm = (w >> 1) * 64, wn = (w & 1) * 64;
    const int l15 = lane & 15, lg = lane >> 4;
#pragma unroll
    for (int m = 0; m < 4; ++m)
#pragma unroll
        for (int n = 0; n < 4; ++n)
#pragma unroll
            for (int r = 0; r < 4; ++r) {
                int gr = mrow + wm + m * 16 + lg * 4 + r;   // b*2048 + s
                int gc = ncol + wn + n * 16 + l15;          // h*64 + d
                int b = gr >> 11, s = gr & 2047, h = gc >> 6, d = gc & 63;
                if (z == 0) {
                    qb[((b * 16 + h) * 2048 + s) * 64 + d] = f2bf(acc[m][n][r]);
                } else {
                    int idx = ((b * 16 + h) * 4096 + 2048 + s) * 64 + d;
                    if (z == 1) { kc[idx] = acc[m][n][r]; if (kb) kb[idx] = f2bf(acc[m][n][r]); }
                    else         vc[idx] = acc[m][n][r];
                }
            }

    if (z == 2 && vbT) {
#pragma unroll
        for (int m = 0; m < 4; ++m)
#pragma unroll
            for (int n = 0; n < 4; ++n)
#pragma unroll
                for (int r = 0; r < 4; ++r)
                    smem[(wn + n * 16 + l15) * 136 + wm + m * 16 + lg * 4 + r] =
                        f2bf(acc[m][n][r]);
        __syncthreads();
        const int c = t >> 1, half = t & 1;
        const int gc = ncol + c, h2 = gc >> 6, d2 = gc & 63;
        const int bb = mrow >> 11, sbase = mrow & 2047;
        u16* dst = vbT + (size_t)((bb * 16 + h2) * 64 + d2) * 4096 + 2048 + sbase + half * 64;
        const u16* srcp = &smem[c * 136 + half * 64];
#pragma unroll
        for (int j = 0; j < 8; ++j)
            ((uint4*)dst)[j] = *(const uint4*)&srcp[j * 8];
    }
}

// ============ O projection: A bf16 x WT bf16 -> out f32 ============
__global__ __launch_bounds__(256) void k_gemm_o(const u16* A, const u16* WT, float* out) {
    __shared__ u16 lds_a[128 * 32];
    __shared__ u16 lds_b[128 * 32];
    const int mrow = blockIdx.x * 128, ncol = blockIdx.y * 128;

    f32x4 acc[4][4];
#pragma unroll
    for (int m = 0; m < 4; ++m)
#pragma unroll
        for (int n = 0; n < 4; ++n) acc[m][n] = (f32x4){0.f, 0.f, 0.f, 0.f};

    gemm_loop(A, WT, mrow, ncol, lds_a, lds_b, acc);

    const int t = threadIdx.x, lane = t & 63, w = t >> 6;
    const int wm = (w >> 1) * 64, wn = (w & 1) * 64;
    const int l15 = lane & 15, lg = lane >> 4;
#pragma unroll
    for (int m = 0; m < 4; ++m)
#pragma unroll
        for (int n = 0; n < 4; ++n)
#pragma unroll
            for (int r = 0; r < 4; ++r) {
                int gr = mrow + wm + m * 16 + lg * 4 + r;
                int gc = ncol + wn + n * 16 + l15;
                out[gr * 1024 + gc] = acc[m][n][r];
            }
}

// ============ FAST attention v8: unroll-2 KV loop, compile-time buffer bases ============
// grid 512 (XCD-swizzled). 8 waves x 16 qrows (QBLK=128). KV tile 64, K+V dbuf,
// single barrier per tile. Identical schedule/math to round-12 best; the loop is
// unrolled x2 so all lk/lv/lp addresses constant-fold per body.
#define LOG2E_SCALE 0.18033688f   // 0.125 * log2(e)
#define RESCALE_THR 11.0f         // log2 units; P bounded by 2^11
__global__ __launch_bounds__(512) void k_attn_c(const u16* __restrict__ qb,
                                                const u16* __restrict__ kb,
                                                const u16* __restrict__ vbT,
                                                u16* __restrict__ aws) {
    __shared__ u16 lk[2][4096];
    __shared__ u16 lv[2][4096];
    __shared__ u16 lp[8][16 * 72];

    const int t = threadIdx.x, lane = t & 63, w = t >> 6;
    const int l15 = lane & 15, lg = lane >> 4;
    const int n = blockIdx.x;
    const int wg = (n & 7) * 64 + (n >> 3);       // XCD bijection (512 % 8 == 0)
    const int qt = wg & 15, bh = wg >> 4;
    const int b = bh >> 4, h = bh & 15;

    const u16* Qb  = qb + (bh * 2048 + qt * 128 + w * 16) * 64;
    const u16* Kbh = kb + bh * (ST * 64);
    const u16* VbT = vbT + bh * (64 * ST);

    const int kr = t >> 3, kc8 = t & 7;
    const int swz8 = (kc8 ^ (kr & 7)) * 8;
    const int srcK = kr * 64 + swz8;
    const int srcV = kr * ST + swz8;

    bf16x8 qf[2];
#pragma unroll
    for (int ds = 0; ds < 2; ++ds)
        qf[ds] = *(const bf16x8*)&Qb[l15 * 64 + ds * 32 + lg * 8];

    f32x4 o[4];
    float m_ = -INFINITY, ls = 0.f;
#pragma unroll
    for (int i = 0; i < 4; ++i) o[i] = (f32x4){0.f, 0.f, 0.f, 0.f};

    gload_lds16(Kbh + srcK, &lk[0][t * 8]);
    gload_lds16(VbT + srcV, &lv[0][t * 8]);
    __syncthreads();

    // tile body with compile-time buffer index CUR
#define TILE_BODY(CUR, NXT, KT)                                                             \
    {                                                                                       \
        const bool more = ((KT) + 1 < ST / 64);                                             \
        if (more) {                                                                         \
            gload_lds16(Kbh + ((KT) + 1) * 4096 + srcK, &lk[NXT][t * 8]);                   \
            gload_lds16(VbT + ((KT) + 1) * 64 + srcV, &lv[NXT][t * 8]);                     \
        }                                                                                   \
        f32x4 s[4];                                                                         \
        __builtin_amdgcn_s_setprio(1);                                                      \
        _Pragma("unroll")                                                                   \
        for (int ni = 0; ni < 4; ++ni) {                                                    \
            f32x4 a = (f32x4){0.f, 0.f, 0.f, 0.f};                                          \
            _Pragma("unroll")                                                               \
            for (int ds = 0; ds < 2; ++ds) {                                                \
                bf16x8 kf = *(const bf16x8*)&lk[CUR][(ni * 16 + l15) * 64 +                 \
                                                    (((ds * 4 + lg) ^ (l15 & 7)) * 8)];     \
                a = __builtin_amdgcn_mfma_f32_16x16x32_bf16(kf, qf[ds], a, 0, 0, 0);        \
            }                                                                               \
            s[ni] = a * LOG2E_SCALE;                                                        \
        }                                                                                   \
        __builtin_amdgcn_s_setprio(0);                                                      \
        float t0 = fmaxf(fmaxf(s[0][0], s[0][1]), fmaxf(s[0][2], s[0][3]));                 \
        float t1 = fmaxf(fmaxf(s[1][0], s[1][1]), fmaxf(s[1][2], s[1][3]));                 \
        float t2 = fmaxf(fmaxf(s[2][0], s[2][1]), fmaxf(s[2][2], s[2][3]));                 \
        float t3 = fmaxf(fmaxf(s[3][0], s[3][1]), fmaxf(s[3][2], s[3][3]));                 \
        float tm = fmaxf(fmaxf(t0, t1), fmaxf(t2, t3));                                     \
        if (__any(tm > m_ + RESCALE_THR)) {                                                 \
            tm = fmaxf(tm, __shfl_xor(tm, 16));                                             \
            tm = fmaxf(tm, __shfl_xor(tm, 32));                                             \
            float mn = fmaxf(m_, tm);                                                       \
            float corr = exp2f(m_ - mn);                                                    \
            ls *= corr;                                                                     \
            m_ = mn;                                                                        \
            _Pragma("unroll")                                                               \
            for (int r = 0; r < 4; ++r) {                                                   \
                float cr = __shfl(corr, lg * 4 + r);                                        \
                _Pragma("unroll")                                                           \
                for (int dt = 0; dt < 4; ++dt) o[dt][r] *= cr;                              \
            }                                                                               \
        }                                                                                   \
        _Pragma("unroll")                                                                   \
        for (int ni = 0; ni < 4; ++ni) {                                                    \
            float p0 = exp2f(s[ni][0] - m_);                                                \
            float p1 = exp2f(s[ni][1] - m_);                                                \
            float p2 = exp2f(s[ni][2] - m_);                                                \
            float p3 = exp2f(s[ni][3] - m_);                                                \
            ls += (p0 + p1) + (p2 + p3);                                                    \
            *(uint2*)&lp[w][l15 * 72 + ni * 16 + lg * 4] =                                  \
                make_uint2(cvtpk(p0, p1), cvtpk(p2, p3));                                   \
        }                                                                                   \
        bf16x8 pf[2];                                                                       \
        _Pragma("unroll")                                                                   \
        for (int kss = 0; kss < 2; ++kss)                                                   \
            pf[kss] = *(const bf16x8*)&lp[w][l15 * 72 + kss * 32 + lg * 8];                 \
        __builtin_amdgcn_s_setprio(1);                                                      \
        _Pragma("unroll")                                                                   \
        for (int dt = 0; dt < 4; ++dt) {                                                    \
            const int dd = dt * 16 + l15;                                                   \
            _Pragma("unroll")                                                               \
            for (int kss = 0; kss < 2; ++kss) {                                             \
                bf16x8 vf = *(const bf16x8*)&lv[CUR][dd * 64 +                              \
                                                    (((kss * 4 + lg) ^ (dd & 7)) * 8)];     \
                o[dt] = __builtin_amdgcn_mfma_f32_16x16x32_bf16(pf[kss], vf, o[dt], 0, 0, 0);\
            }                                                                               \
        }                                                                                   \
        __builtin_amdgcn_s_setprio(0);                                                      \
        __syncthreads();                                                                    \
    }

    for (int kt = 0; kt < ST / 64; kt += 2) {
        TILE_BODY(0, 1, kt)
        TILE_BODY(1, 0, kt + 1)
    }
#undef TILE_BODY

    ls += __shfl_xor(ls, 16);
    ls += __shfl_xor(ls, 32);
    const int qrow = qt * 128 + w * 16 + lg * 4;
#pragma unroll
    for (int r = 0; r < 4; ++r) {
        float lr = __shfl(ls, lg * 4 + r);
        float inv = 1.f / lr;
#pragma unroll
        for (int dt = 0; dt < 4; ++dt) {
            int sg = qrow + r;
            int col = h * 64 + dt * 16 + l15;
            aws[(b * 2048 + sg) * 1024 + col] = f2bf(o[dt][r] * inv);
        }
    }
}

// ============ FALLBACK attention (round-7 proven, f32 caches) ============
__global__ __launch_bounds__(256) void k_attn(const u16* qb, const float* kc,
                                              const float* vc, u16* aws) {
    __shared__ u16 lk[64 * 72];
    __shared__ u16 lvt[64 * 72];
    __shared__ u16 lp[4][16 * 72];

    const int t = threadIdx.x, lane = t & 63, w = t >> 6;
    const int l15 = lane & 15, lg = lane >> 4;
    const int qt = blockIdx.x;
    const int bh = blockIdx.y;
    const int b = bh >> 4, h = bh & 15;

    const u16* Qb = qb + (bh * 2048 + qt * 64 + w * 16) * 64;
    const float* Kb = kc + bh * (ST * 64);
    const float* Vb = vc + bh * (ST * 64);

    bf16x8 qf[2];
#pragma unroll
    for (int ds = 0; ds < 2; ++ds)
        qf[ds] = *(const bf16x8*)&Qb[l15 * 64 + ds * 32 + lg * 8];

    f32x4 o[4];
    float m_[4], ls[4];
#pragma unroll
    for (int i = 0; i < 4; ++i) { o[i] = (f32x4){0.f, 0.f, 0.f, 0.f}; m_[i] = -INFINITY; ls[i] = 0.f; }

    for (int kt = 0; kt < ST / 64; ++kt) {
        const float* ks = Kb + kt * 64 * 64;
        const float* vs = Vb + kt * 64 * 64;
#pragma unroll
        for (int p = 0; p < 2; ++p) {
            int r = (t >> 3) + p * 32, c8 = (t & 7) * 8;
            const float4* k4 = (const float4*)&ks[r * 64 + c8];
            *(uint4*)&lk[r * 72 + c8] = pack8(k4[0], k4[1]);
            const float4* v4 = (const float4*)&vs[r * 64 + c8];
            uint4 vv = pack8(v4[0], v4[1]);
            const u16* e = (const u16*)&vv;
#pragma unroll
            for (int j = 0; j < 8; ++j) lvt[(c8 + j) * 72 + r] = e[j];
        }
        __syncthreads();

        f32x4 s[4];
#pragma unroll
        for (int ni = 0; ni < 4; ++ni) {
            f32x4 a = (f32x4){0.f, 0.f, 0.f, 0.f};
#pragma unroll
            for (int ds = 0; ds < 2; ++ds) {
                bf16x8 kf = *(const bf16x8*)&lk[(ni * 16 + l15) * 72 + ds * 32 + lg * 8];
                a = __builtin_amdgcn_mfma_f32_16x16x32_bf16(qf[ds], kf, a, 0, 0, 0);
            }
            s[ni] = a * 0.125f;
        }

#pragma unroll
        for (int r = 0; r < 4; ++r) {
            float tm = fmaxf(fmaxf(s[0][r], s[1][r]), fmaxf(s[2][r], s[3][r]));
#pragma unroll
            for (int off = 1; off < 16; off <<= 1) tm = fmaxf(tm, __shfl_xor(tm, off));
            float mn = fmaxf(m_[r], tm);
            float corr = __expf(m_[r] - mn);
            float rs = 0.f;
#pragma unroll
            for (int ni = 0; ni < 4; ++ni) {
                float p = __expf(s[ni][r] - mn);
                s[ni][r] = p;
                rs += p;
            }
#pragma unroll
            for (int off = 1; off < 16; off <<= 1) rs += __shfl_xor(rs, off);
            ls[r] = ls[r] * corr + rs;
            m_[r] = mn;
#pragma unroll
            for (int dt = 0; dt < 4; ++dt) o[dt][r] *= corr;
        }

#pragma unroll
        for (int ni = 0; ni < 4; ++ni)
#pragma unroll
            for (int r = 0; r < 4; ++r)
                lp[w][(lg * 4 + r) * 72 + ni * 16 + l15] = f2bf(s[ni][r]);

#pragma unroll
        for (int dt = 0; dt < 4; ++dt) {
#pragma unroll
            for (int kss = 0; kss < 2; ++kss) {
                bf16x8 pf = *(const bf16x8*)&lp[w][l15 * 72 + kss * 32 + lg * 8];
                bf16x8 vf = *(const bf16x8*)&lvt[(dt * 16 + l15) * 72 + kss * 32 + lg * 8];
                o[dt] = __builtin_amdgcn_mfma_f32_16x16x32_bf16(pf, vf, o[dt], 0, 0, 0);
            }
        }
        __syncthreads();
    }

    const int qrow = qt * 64 + w * 16 + lg * 4;
#pragma unroll
    for (int r = 0; r < 4; ++r) {
        float inv = 1.f / ls[r];
#pragma unroll
        for (int dt = 0; dt < 4; ++dt) {
            int sg = qrow + r;
            int col = h * 64 + dt * 16 + l15;
            aws[(b * 2048 + sg) * 1024 + col] = f2bf(o[dt][r] * inv);
        }
    }
}

extern "C" void kernel_launch(void* const* d_in, const int* in_sizes, int n_in,
                              void* d_out, int out_size, void* d_ws, size_t ws_size,
                              hipStream_t stream) {
    const float* x   = (const float*)d_in[0];
    const float* kvk = (const float*)d_in[1];
    const float* kvv = (const float*)d_in[2];
    const float* wq  = (const float*)d_in[3];
    const float* wk  = (const float*)d_in[4];
    const float* wv  = (const float*)d_in[5];
    const float* wo  = (const float*)d_in[6];

    float* out = (float*)d_out;                // [2,2048,1024] f32 (output 0)
    float* kc  = out + 4194304;                // [2,16,4096,64] f32 (output 1)
    float* vc  = kc + 8388608;                 // [2,16,4096,64] f32 (output 2)

    u16* qb = (u16*)d_out;                     // Q bf16 parked in out[0 : 8.39MB]
    u16* xb = (u16*)d_out + 4194304;           // x bf16 in out[8.39 : 16.78MB]

    if (ws_size >= (size_t)50331648) {
        // ws: wt(8.39) | kb(16.78) | vbT(16.78) | aws(8.39) = 50.33MB
        u16* wt  = (u16*)d_ws;
        u16* kb  = wt + 4194304;
        u16* vbT = kb + 8388608;
        u16* aws = vbT + 8388608;

        k_prep<<<dim3(4096), dim3(256), 0, stream>>>(x, xb, wq, wk, wv, wo, wt,
                                                     kvk, kvv, kc, vc, kb, vbT);
        k_gemm_qkv<<<dim3(32, 8, 3), dim3(256), 0, stream>>>(xb, wt, qb, kc, vc, kb, vbT);
        k_attn_c<<<dim3(512), dim3(512), 0, stream>>>(qb, kb, vbT, aws);
        k_gemm_o<<<dim3(32, 8), dim3(256), 0, stream>>>(aws, wt + 3 * 1048576, out);
    } else {
        // round-7 proven fallback
        u16* wt  = (u16*)d_ws;
        u16* xb2 = wt + 4 * 1048576;
        u16* aws = xb2;

        k_cvt_x<<<dim3(2048), dim3(256), 0, stream>>>(x, xb2);
        k_transpose<<<dim3(16, 16, 4), dim3(256), 0, stream>>>(wq, wk, wv, wo, wt);
        k_copy_cache<<<dim3(4096), dim3(256), 0, stream>>>((const float4*)kvk, (const float4*)kvv,
                                                           (float4*)kc, (float4*)vc);
        k_gemm_qkv<<<dim3(32, 8, 3), dim3(256), 0, stream>>>(xb2, wt, qb, kc, vc, nullptr, nullptr);
        k_attn<<<dim3(32, 32), dim3(256), 0, stream>>>(qb, kc, vc, aws);
        k_gemm_o<<<dim3(32, 8), dim3(256), 0, stream>>>(aws, wt + 3 * 1048576, out);
    }
}